// Round 1
// baseline (609.556 us; speedup 1.0000x reference)
//
#include <hip/hip_runtime.h>
#include <math.h>

#define N_NODES 50000
#define N_EDGES 800000
#define ETOT    (N_EDGES + N_NODES)

// ---------------------------------------------------------------- CSR build

__global__ void hist_k(const int* __restrict__ ei, int* __restrict__ counts) {
    int e = blockIdx.x * blockDim.x + threadIdx.x;
    if (e >= ETOT) return;
    int d = (e < N_EDGES) ? ei[N_EDGES + e] : (e - N_EDGES);
    atomicAdd(&counts[d], 1);
}

__global__ void __launch_bounds__(1024) scan_k(const int* __restrict__ counts,
                                               int* __restrict__ offsets) {
    __shared__ int sums[1024];
    const int n = N_NODES;
    const int C = (n + 1023) / 1024;  // 49
    int t = threadIdx.x;
    int base = t * C;
    int local = 0;
    for (int k = 0; k < C; ++k) {
        int i = base + k;
        if (i < n) local += counts[i];
    }
    sums[t] = local;
    __syncthreads();
    for (int off = 1; off < 1024; off <<= 1) {
        int v = (t >= off) ? sums[t - off] : 0;
        __syncthreads();
        sums[t] += v;
        __syncthreads();
    }
    int run = (t == 0) ? 0 : sums[t - 1];
    for (int k = 0; k < C; ++k) {
        int i = base + k;
        if (i < n) { offsets[i] = run; run += counts[i]; }
    }
    if (t == 1023) offsets[n] = sums[1023];
}

__global__ void scatter_k(const int* __restrict__ ei, const int* __restrict__ offsets,
                          int* __restrict__ fill, int* __restrict__ srcs) {
    int e = blockIdx.x * blockDim.x + threadIdx.x;
    if (e >= ETOT) return;
    int s, d;
    if (e < N_EDGES) { s = ei[e]; d = ei[N_EDGES + e]; }
    else             { s = e - N_EDGES; d = s; }
    int pos = offsets[d] + atomicAdd(&fill[d], 1);
    srcs[pos] = s;
}

// ---------------------------------------------------------------- GEMM  (K=128, NCOL=128; B staged in LDS)
// If B1 != nullptr, B = [B0 | B1] where B0,B1 are [128 x 64].

__global__ void __launch_bounds__(256) gemm128_k(const float* __restrict__ A,
                                                 const float* __restrict__ B0,
                                                 const float* __restrict__ B1,
                                                 float* __restrict__ C, int M) {
    __shared__ float Blds[128 * 128];
    __shared__ float Alds[8 * 128];
    int t = threadIdx.x;

    // stage B: 4096 float4 slots
    for (int q = t; q < 128 * 32; q += 256) {
        int row = q >> 5, cs = q & 31;
        float4 v;
        if (B1 == nullptr) {
            v = ((const float4*)B0)[row * 32 + cs];
        } else {
            if (cs < 16) v = ((const float4*)B0)[row * 16 + cs];
            else         v = ((const float4*)B1)[row * 16 + (cs - 16)];
        }
        ((float4*)Blds)[q] = v;
    }
    __syncthreads();

    int row = t >> 5, cg = t & 31;
    int tiles = M / 8;
    for (int tile = blockIdx.x; tile < tiles; tile += gridDim.x) {
        int r0 = tile * 8;
        ((float4*)Alds)[t] = ((const float4*)A)[r0 * 32 + t];
        __syncthreads();
        float4 acc = make_float4(0.f, 0.f, 0.f, 0.f);
        const float* arow = &Alds[row * 128];
#pragma unroll 8
        for (int k = 0; k < 128; ++k) {
            float a = arow[k];
            float4 b = ((float4*)Blds)[k * 32 + cg];
            acc.x += a * b.x; acc.y += a * b.y; acc.z += a * b.z; acc.w += a * b.w;
        }
        ((float4*)C)[(r0 + row) * 32 + cg] = acc;
        __syncthreads();
    }
}

// ---------------------------------------------------------------- attention coefficients

// layer 1: h [N,2,64] (row=128 floats). lane l holds elems 2l,2l+1. head = l>>5.
__global__ void attn1_k(const float* __restrict__ h, const float* __restrict__ attl,
                        const float* __restrict__ attr, float* __restrict__ al,
                        float* __restrict__ ar) {
    int wid = (blockIdx.x * blockDim.x + threadIdx.x) >> 6;
    int l = threadIdx.x & 63;
    if (wid >= N_NODES) return;
    float2 hv = ((const float2*)(h + (size_t)wid * 128))[l];
    int head = l >> 5;
    float2 alv = ((const float2*)(attl + head * 64))[l & 31];
    float2 arv = ((const float2*)(attr + head * 64))[l & 31];
    float pl = hv.x * alv.x + hv.y * alv.y;
    float pr = hv.x * arv.x + hv.y * arv.y;
#pragma unroll
    for (int m = 1; m < 32; m <<= 1) {
        pl += __shfl_xor(pl, m);
        pr += __shfl_xor(pr, m);
    }
    if ((l & 31) == 0) {
        al[wid * 2 + head] = pl;
        ar[wid * 2 + head] = pr;
    }
}

// layers 2+3 fused: hcat [N,128] = [mu(2x32) | ls(2x32)]. lane l holds elems 2l,2l+1.
// group g = l>>4 : 0=mu-h0, 1=mu-h1, 2=ls-h0, 3=ls-h1.
__global__ void attn23_k(const float* __restrict__ hcat,
                         const float* __restrict__ attlmu, const float* __restrict__ attrmu,
                         const float* __restrict__ attlls, const float* __restrict__ attrls,
                         float* __restrict__ alc, float* __restrict__ arc) {
    int wid = (blockIdx.x * blockDim.x + threadIdx.x) >> 6;
    int l = threadIdx.x & 63;
    if (wid >= N_NODES) return;
    float2 hv = ((const float2*)(hcat + (size_t)wid * 128))[l];
    int g = l >> 4;
    int head = g & 1;
    const float* attl = (l < 32) ? attlmu : attlls;
    const float* attr = (l < 32) ? attrmu : attrls;
    int cpair = l & 15;  // float2 index within 32-ch head
    float2 alv = ((const float2*)(attl + head * 32))[cpair];
    float2 arv = ((const float2*)(attr + head * 32))[cpair];
    float pl = hv.x * alv.x + hv.y * alv.y;
    float pr = hv.x * arv.x + hv.y * arv.y;
#pragma unroll
    for (int m = 1; m < 16; m <<= 1) {
        pl += __shfl_xor(pl, m);
        pr += __shfl_xor(pr, m);
    }
    if ((l & 15) == 0) {
        alc[wid * 4 + g] = pl;
        arc[wid * 4 + g] = pr;
    }
}

// ---------------------------------------------------------------- edge aggregation (online softmax)

__device__ __forceinline__ float sigmoidf_fast(float x) {
    return 1.f / (1.f + __expf(-x));
}

// layer 1: wave per dst node. per-head logit over 64 ch (32 lanes x 2).
// epilogue: /denom, +b1, ELU -> h2.
__global__ void __launch_bounds__(256) edge1_k(const float* __restrict__ h1,
                                               const float* __restrict__ al,
                                               const float* __restrict__ ar,
                                               const int* __restrict__ offsets,
                                               const int* __restrict__ srcs,
                                               const float* __restrict__ b1,
                                               float* __restrict__ h2) {
    int i = (blockIdx.x * blockDim.x + threadIdx.x) >> 6;
    int l = threadIdx.x & 63;
    if (i >= N_NODES) return;
    int head = l >> 5;
    float2 hi = ((const float2*)(h1 + (size_t)i * 128))[l];
    float ari = ar[i * 2 + head];
    int start = offsets[i], end = offsets[i + 1];
    float m = -3.0e38f, s = 0.f, o0 = 0.f, o1 = 0.f;
    for (int p = start; p < end; ++p) {
        int j = srcs[p];
        float2 hj = ((const float2*)(h1 + (size_t)j * 128))[l];
        float part = hi.x * hj.x + hi.y * hj.y;
        part += __shfl_xor(part, 1);
        part += __shfl_xor(part, 2);
        part += __shfl_xor(part, 4);
        part += __shfl_xor(part, 8);
        part += __shfl_xor(part, 16);
        float a = (al[j * 2 + head] + ari) * sigmoidf_fast(part);
        a = (a > 0.f) ? a : 0.2f * a;
        float mn = fmaxf(m, a);
        float corr = __expf(m - mn);
        float w = __expf(a - mn);
        s = s * corr + w;
        o0 = o0 * corr + w * hj.x;
        o1 = o1 * corr + w * hj.y;
        m = mn;
    }
    float inv = 1.f / (s + 1e-16f);
    float2 bv = ((const float2*)b1)[l];
    float r0 = o0 * inv + bv.x;
    float r1 = o1 * inv + bv.y;
    r0 = (r0 > 0.f) ? r0 : (__expf(r0) - 1.f);
    r1 = (r1 > 0.f) ? r1 : (__expf(r1) - 1.f);
    ((float2*)(h2 + (size_t)i * 128))[l] = make_float2(r0, r1);
}

// layers 2+3 fused: wave per dst node, 16-lane groups per (branch,head).
// logit over 32 ch (16 lanes x 2). writes mu / logstd directly to d_out.
__global__ void __launch_bounds__(256) edge23_k(const float* __restrict__ hcat,
                                                const float* __restrict__ alc,
                                                const float* __restrict__ arc,
                                                const int* __restrict__ offsets,
                                                const int* __restrict__ srcs,
                                                const float* __restrict__ bmu,
                                                const float* __restrict__ bls,
                                                float* __restrict__ out) {
    int i = (blockIdx.x * blockDim.x + threadIdx.x) >> 6;
    int l = threadIdx.x & 63;
    if (i >= N_NODES) return;
    int g = l >> 4;
    float2 hi = ((const float2*)(hcat + (size_t)i * 128))[l];
    float ari = arc[i * 4 + g];
    int start = offsets[i], end = offsets[i + 1];
    float m = -3.0e38f, s = 0.f, o0 = 0.f, o1 = 0.f;
    for (int p = start; p < end; ++p) {
        int j = srcs[p];
        float2 hj = ((const float2*)(hcat + (size_t)j * 128))[l];
        float part = hi.x * hj.x + hi.y * hj.y;
        part += __shfl_xor(part, 1);
        part += __shfl_xor(part, 2);
        part += __shfl_xor(part, 4);
        part += __shfl_xor(part, 8);
        float a = (alc[j * 4 + g] + ari) * sigmoidf_fast(part);
        a = (a > 0.f) ? a : 0.2f * a;
        float mn = fmaxf(m, a);
        float corr = __expf(m - mn);
        float w = __expf(a - mn);
        s = s * corr + w;
        o0 = o0 * corr + w * hj.x;
        o1 = o1 * corr + w * hj.y;
        m = mn;
    }
    float inv = 1.f / (s + 1e-16f);
    int e0 = 2 * l;
    int br = l >> 5;           // 0 = mu, 1 = logstd
    int e6 = e0 & 63;          // element within branch row (64)
    const float* b = br ? bls : bmu;
    float r0 = o0 * inv + b[e6];
    float r1 = o1 * inv + b[e6 + 1];
    float* dst = out + (size_t)br * (N_NODES * 64) + (size_t)i * 64 + e6;
    dst[0] = r0;
    dst[1] = r1;
}

// ---------------------------------------------------------------- launcher

extern "C" void kernel_launch(void* const* d_in, const int* in_sizes, int n_in,
                              void* d_out, int out_size, void* d_ws, size_t ws_size,
                              hipStream_t stream) {
    const float* x      = (const float*)d_in[0];
    const int*   ei     = (const int*)d_in[1];
    const float* W1     = (const float*)d_in[2];
    const float* att_l1 = (const float*)d_in[3];
    const float* att_r1 = (const float*)d_in[4];
    const float* b1     = (const float*)d_in[5];
    const float* Wmu    = (const float*)d_in[6];
    const float* attlmu = (const float*)d_in[7];
    const float* attrmu = (const float*)d_in[8];
    const float* bmu    = (const float*)d_in[9];
    const float* Wls    = (const float*)d_in[10];
    const float* attlls = (const float*)d_in[11];
    const float* attrls = (const float*)d_in[12];
    const float* bls    = (const float*)d_in[13];
    float* out = (float*)d_out;

    // workspace layout (floats then ints, 16B aligned)
    float* h1pre = (float*)d_ws;              // 6,400,000
    float* h2    = h1pre + 6400000;           // 6,400,000
    float* hcat  = h2 + 6400000;              // 6,400,000
    float* al1   = hcat + 6400000;            // 100,000
    float* ar1   = al1 + 100000;              // 100,000
    float* alc   = ar1 + 100000;              // 200,000
    float* arc   = alc + 200000;              // 200,000
    int* counts  = (int*)(arc + 200000);      // 50,000
    int* fill    = counts + 50000;            // 50,000
    int* offsets = fill + 50000;              // 50,001 (padded to 50016)
    int* srcs    = offsets + 50016;           // 850,000

    hipMemsetAsync(counts, 0, 50000 * sizeof(int), stream);
    hipMemsetAsync(fill, 0, 50000 * sizeof(int), stream);

    int ethreads = 256;
    int eblocks = (ETOT + ethreads - 1) / ethreads;
    hist_k<<<eblocks, ethreads, 0, stream>>>(ei, counts);
    scan_k<<<1, 1024, 0, stream>>>(counts, offsets);
    scatter_k<<<eblocks, ethreads, 0, stream>>>(ei, offsets, fill, srcs);

    gemm128_k<<<512, 256, 0, stream>>>(x, W1, nullptr, h1pre, N_NODES);

    int nblocks = (N_NODES + 3) / 4;  // 4 waves (nodes) per 256-thread block
    attn1_k<<<nblocks, 256, 0, stream>>>(h1pre, att_l1, att_r1, al1, ar1);
    edge1_k<<<nblocks, 256, 0, stream>>>(h1pre, al1, ar1, offsets, srcs, b1, h2);

    gemm128_k<<<512, 256, 0, stream>>>(h2, Wmu, Wls, hcat, N_NODES);
    attn23_k<<<nblocks, 256, 0, stream>>>(hcat, attlmu, attrmu, attlls, attrls, alc, arc);
    edge23_k<<<nblocks, 256, 0, stream>>>(hcat, alc, arc, offsets, srcs, bmu, bls, out);
}

// Round 2
// 524.853 us; speedup vs baseline: 1.1614x; 1.1614x over previous
//
#include <hip/hip_runtime.h>
#include <math.h>

#define N_NODES 50000
#define N_EDGES 800000
#define ETOT    (N_EDGES + N_NODES)

// ---------------------------------------------------------------- CSR build

__global__ void hist_k(const int* __restrict__ ei, int* __restrict__ counts) {
    int e = blockIdx.x * blockDim.x + threadIdx.x;
    if (e >= ETOT) return;
    int d = (e < N_EDGES) ? ei[N_EDGES + e] : (e - N_EDGES);
    atomicAdd(&counts[d], 1);
}

__global__ void __launch_bounds__(1024) scan_k(const int* __restrict__ counts,
                                               int* __restrict__ offsets) {
    __shared__ int sums[1024];
    const int n = N_NODES;
    const int C = (n + 1023) / 1024;  // 49
    int t = threadIdx.x;
    int base = t * C;
    int local = 0;
    for (int k = 0; k < C; ++k) {
        int i = base + k;
        if (i < n) local += counts[i];
    }
    sums[t] = local;
    __syncthreads();
    for (int off = 1; off < 1024; off <<= 1) {
        int v = (t >= off) ? sums[t - off] : 0;
        __syncthreads();
        sums[t] += v;
        __syncthreads();
    }
    int run = (t == 0) ? 0 : sums[t - 1];
    for (int k = 0; k < C; ++k) {
        int i = base + k;
        if (i < n) { offsets[i] = run; run += counts[i]; }
    }
    if (t == 1023) offsets[n] = sums[1023];
}

__global__ void scatter_k(const int* __restrict__ ei, const int* __restrict__ offsets,
                          int* __restrict__ fill, int* __restrict__ srcs) {
    int e = blockIdx.x * blockDim.x + threadIdx.x;
    if (e >= ETOT) return;
    int s, d;
    if (e < N_EDGES) { s = ei[e]; d = ei[N_EDGES + e]; }
    else             { s = e - N_EDGES; d = s; }
    int pos = offsets[d] + atomicAdd(&fill[d], 1);
    srcs[pos] = s;
}

// ---------------------------------------------------------------- GEMM  (K=128, NCOL=128; B staged in LDS)

__global__ void __launch_bounds__(256) gemm128_k(const float* __restrict__ A,
                                                 const float* __restrict__ B0,
                                                 const float* __restrict__ B1,
                                                 float* __restrict__ C, int M) {
    __shared__ float Blds[128 * 128];
    __shared__ float Alds[8 * 128];
    int t = threadIdx.x;

    for (int q = t; q < 128 * 32; q += 256) {
        int row = q >> 5, cs = q & 31;
        float4 v;
        if (B1 == nullptr) {
            v = ((const float4*)B0)[row * 32 + cs];
        } else {
            if (cs < 16) v = ((const float4*)B0)[row * 16 + cs];
            else         v = ((const float4*)B1)[row * 16 + (cs - 16)];
        }
        ((float4*)Blds)[q] = v;
    }
    __syncthreads();

    int row = t >> 5, cg = t & 31;
    int tiles = M / 8;
    for (int tile = blockIdx.x; tile < tiles; tile += gridDim.x) {
        int r0 = tile * 8;
        ((float4*)Alds)[t] = ((const float4*)A)[r0 * 32 + t];
        __syncthreads();
        float4 acc = make_float4(0.f, 0.f, 0.f, 0.f);
        const float* arow = &Alds[row * 128];
#pragma unroll 8
        for (int k = 0; k < 128; ++k) {
            float a = arow[k];
            float4 b = ((float4*)Blds)[k * 32 + cg];
            acc.x += a * b.x; acc.y += a * b.y; acc.z += a * b.z; acc.w += a * b.w;
        }
        ((float4*)C)[(r0 + row) * 32 + cg] = acc;
        __syncthreads();
    }
}

// ---------------------------------------------------------------- attention coefficients

__global__ void attn1_k(const float* __restrict__ h, const float* __restrict__ attl,
                        const float* __restrict__ attr, float* __restrict__ al,
                        float* __restrict__ ar) {
    int wid = (blockIdx.x * blockDim.x + threadIdx.x) >> 6;
    int l = threadIdx.x & 63;
    if (wid >= N_NODES) return;
    float2 hv = ((const float2*)(h + (size_t)wid * 128))[l];
    int head = l >> 5;
    float2 alv = ((const float2*)(attl + head * 64))[l & 31];
    float2 arv = ((const float2*)(attr + head * 64))[l & 31];
    float pl = hv.x * alv.x + hv.y * alv.y;
    float pr = hv.x * arv.x + hv.y * arv.y;
#pragma unroll
    for (int m = 1; m < 32; m <<= 1) {
        pl += __shfl_xor(pl, m);
        pr += __shfl_xor(pr, m);
    }
    if ((l & 31) == 0) {
        al[wid * 2 + head] = pl;
        ar[wid * 2 + head] = pr;
    }
}

__global__ void attn23_k(const float* __restrict__ hcat,
                         const float* __restrict__ attlmu, const float* __restrict__ attrmu,
                         const float* __restrict__ attlls, const float* __restrict__ attrls,
                         float* __restrict__ alc, float* __restrict__ arc) {
    int wid = (blockIdx.x * blockDim.x + threadIdx.x) >> 6;
    int l = threadIdx.x & 63;
    if (wid >= N_NODES) return;
    float2 hv = ((const float2*)(hcat + (size_t)wid * 128))[l];
    int g = l >> 4;
    int head = g & 1;
    const float* attl = (l < 32) ? attlmu : attlls;
    const float* attr = (l < 32) ? attrmu : attrls;
    int cpair = l & 15;
    float2 alv = ((const float2*)(attl + head * 32))[cpair];
    float2 arv = ((const float2*)(attr + head * 32))[cpair];
    float pl = hv.x * alv.x + hv.y * alv.y;
    float pr = hv.x * arv.x + hv.y * arv.y;
#pragma unroll
    for (int m = 1; m < 16; m <<= 1) {
        pl += __shfl_xor(pl, m);
        pr += __shfl_xor(pr, m);
    }
    if ((l & 15) == 0) {
        alc[wid * 4 + g] = pl;
        arc[wid * 4 + g] = pr;
    }
}

// ---------------------------------------------------------------- edge aggregation

__device__ __forceinline__ float sigmoidf_fast(float x) {
    return 1.f / (1.f + __expf(-x));
}

// layer 1: wave per dst node, TWO edges per iteration (half-wave each).
// Within a half-wave: 16 lanes x float4 per head (2 heads). No running max
// (alphas bounded; clamp at 60). Epilogue: /denom, +b1, ELU -> h2.
__global__ void __launch_bounds__(256) edge1_k(const float* __restrict__ h1,
                                               const float* __restrict__ al,
                                               const float* __restrict__ ar,
                                               const int* __restrict__ offsets,
                                               const int* __restrict__ srcs,
                                               const float* __restrict__ b1,
                                               float* __restrict__ h2) {
    int i = (blockIdx.x * blockDim.x + threadIdx.x) >> 6;
    int l = threadIdx.x & 63;
    if (i >= N_NODES) return;
    int slot = l & 31;          // float4 slot within 128-float row
    int head = (l >> 4) & 1;
    int sub = l >> 5;           // which of the two edges this half-wave handles
    float4 hi = ((const float4*)(h1 + (size_t)i * 128))[slot];
    float ari = ar[i * 2 + head];
    int start = offsets[i], end = offsets[i + 1];
    float s = 0.f;
    float4 o = make_float4(0.f, 0.f, 0.f, 0.f);
    for (int pb = start; pb < end; pb += 2) {
        int p = pb + sub;
        bool valid = (p < end);
        int j = srcs[valid ? p : start];
        float4 hj = ((const float4*)(h1 + (size_t)j * 128))[slot];
        float part = hi.x * hj.x + hi.y * hj.y + hi.z * hj.z + hi.w * hj.w;
        part += __shfl_xor(part, 1);
        part += __shfl_xor(part, 2);
        part += __shfl_xor(part, 4);
        part += __shfl_xor(part, 8);
        float a = (al[j * 2 + head] + ari) * sigmoidf_fast(part);
        a = (a > 0.f) ? a : 0.2f * a;
        a = fminf(a, 60.f);
        float w = valid ? __expf(a) : 0.f;
        s += w;
        o.x += w * hj.x; o.y += w * hj.y; o.z += w * hj.z; o.w += w * hj.w;
    }
    // merge the two half-wave accumulators (plain adds; no max to reconcile)
    s   += __shfl_xor(s, 32);
    o.x += __shfl_xor(o.x, 32);
    o.y += __shfl_xor(o.y, 32);
    o.z += __shfl_xor(o.z, 32);
    o.w += __shfl_xor(o.w, 32);
    if (l < 32) {
        float inv = 1.f / (s + 1e-16f);
        float4 bv = ((const float4*)b1)[slot];
        float4 r;
        r.x = o.x * inv + bv.x;
        r.y = o.y * inv + bv.y;
        r.z = o.z * inv + bv.z;
        r.w = o.w * inv + bv.w;
        r.x = (r.x > 0.f) ? r.x : (__expf(r.x) - 1.f);
        r.y = (r.y > 0.f) ? r.y : (__expf(r.y) - 1.f);
        r.z = (r.z > 0.f) ? r.z : (__expf(r.z) - 1.f);
        r.w = (r.w > 0.f) ? r.w : (__expf(r.w) - 1.f);
        ((float4*)(h2 + (size_t)i * 128))[slot] = r;
    }
}

// layers 2+3 fused: wave per dst node, TWO edges per iteration. Within a
// half-wave: 8 lanes x float4 per (branch,head) group, 4 groups cover the
// 128-float hcat row = [mu h0 | mu h1 | ls h0 | ls h1]. Writes d_out directly.
__global__ void __launch_bounds__(256) edge23_k(const float* __restrict__ hcat,
                                                const float* __restrict__ alc,
                                                const float* __restrict__ arc,
                                                const int* __restrict__ offsets,
                                                const int* __restrict__ srcs,
                                                const float* __restrict__ bmu,
                                                const float* __restrict__ bls,
                                                float* __restrict__ out) {
    int i = (blockIdx.x * blockDim.x + threadIdx.x) >> 6;
    int l = threadIdx.x & 63;
    if (i >= N_NODES) return;
    int slot = l & 31;          // float4 slot within 128-float row
    int g = (l >> 3) & 3;       // 0=mu-h0, 1=mu-h1, 2=ls-h0, 3=ls-h1
    int sub = l >> 5;
    float4 hi = ((const float4*)(hcat + (size_t)i * 128))[slot];
    float ari = arc[i * 4 + g];
    int start = offsets[i], end = offsets[i + 1];
    float s = 0.f;
    float4 o = make_float4(0.f, 0.f, 0.f, 0.f);
    for (int pb = start; pb < end; pb += 2) {
        int p = pb + sub;
        bool valid = (p < end);
        int j = srcs[valid ? p : start];
        float4 hj = ((const float4*)(hcat + (size_t)j * 128))[slot];
        float part = hi.x * hj.x + hi.y * hj.y + hi.z * hj.z + hi.w * hj.w;
        part += __shfl_xor(part, 1);
        part += __shfl_xor(part, 2);
        part += __shfl_xor(part, 4);
        float a = (alc[j * 4 + g] + ari) * sigmoidf_fast(part);
        a = (a > 0.f) ? a : 0.2f * a;
        a = fminf(a, 60.f);
        float w = valid ? __expf(a) : 0.f;
        s += w;
        o.x += w * hj.x; o.y += w * hj.y; o.z += w * hj.z; o.w += w * hj.w;
    }
    s   += __shfl_xor(s, 32);
    o.x += __shfl_xor(o.x, 32);
    o.y += __shfl_xor(o.y, 32);
    o.z += __shfl_xor(o.z, 32);
    o.w += __shfl_xor(o.w, 32);
    if (l < 32) {
        float inv = 1.f / (s + 1e-16f);
        int br = (l >> 4) & 1;              // 0 = mu, 1 = logstd
        int e4 = l & 15;                    // float4 slot within 64-float branch row
        const float* b = br ? bls : bmu;
        float4 bv = ((const float4*)b)[e4];
        float4 r;
        r.x = o.x * inv + bv.x;
        r.y = o.y * inv + bv.y;
        r.z = o.z * inv + bv.z;
        r.w = o.w * inv + bv.w;
        ((float4*)(out + (size_t)br * (N_NODES * 64)))[(size_t)i * 16 + e4] = r;
    }
}

// ---------------------------------------------------------------- launcher

extern "C" void kernel_launch(void* const* d_in, const int* in_sizes, int n_in,
                              void* d_out, int out_size, void* d_ws, size_t ws_size,
                              hipStream_t stream) {
    const float* x      = (const float*)d_in[0];
    const int*   ei     = (const int*)d_in[1];
    const float* W1     = (const float*)d_in[2];
    const float* att_l1 = (const float*)d_in[3];
    const float* att_r1 = (const float*)d_in[4];
    const float* b1     = (const float*)d_in[5];
    const float* Wmu    = (const float*)d_in[6];
    const float* attlmu = (const float*)d_in[7];
    const float* attrmu = (const float*)d_in[8];
    const float* bmu    = (const float*)d_in[9];
    const float* Wls    = (const float*)d_in[10];
    const float* attlls = (const float*)d_in[11];
    const float* attrls = (const float*)d_in[12];
    const float* bls    = (const float*)d_in[13];
    float* out = (float*)d_out;

    float* h1pre = (float*)d_ws;              // 6,400,000
    float* h2    = h1pre + 6400000;           // 6,400,000
    float* hcat  = h2 + 6400000;              // 6,400,000
    float* al1   = hcat + 6400000;            // 100,000
    float* ar1   = al1 + 100000;              // 100,000
    float* alc   = ar1 + 100000;              // 200,000
    float* arc   = alc + 200000;              // 200,000
    int* counts  = (int*)(arc + 200000);      // 50,000
    int* fill    = counts + 50000;            // 50,000
    int* offsets = fill + 50000;              // 50,016
    int* srcs    = offsets + 50016;           // 850,000

    hipMemsetAsync(counts, 0, 50000 * sizeof(int), stream);
    hipMemsetAsync(fill, 0, 50000 * sizeof(int), stream);

    int ethreads = 256;
    int eblocks = (ETOT + ethreads - 1) / ethreads;
    hist_k<<<eblocks, ethreads, 0, stream>>>(ei, counts);
    scan_k<<<1, 1024, 0, stream>>>(counts, offsets);
    scatter_k<<<eblocks, ethreads, 0, stream>>>(ei, offsets, fill, srcs);

    gemm128_k<<<512, 256, 0, stream>>>(x, W1, nullptr, h1pre, N_NODES);

    int nblocks = (N_NODES + 3) / 4;
    attn1_k<<<nblocks, 256, 0, stream>>>(h1pre, att_l1, att_r1, al1, ar1);
    edge1_k<<<nblocks, 256, 0, stream>>>(h1pre, al1, ar1, offsets, srcs, b1, h2);

    gemm128_k<<<512, 256, 0, stream>>>(h2, Wmu, Wls, hcat, N_NODES);
    attn23_k<<<nblocks, 256, 0, stream>>>(hcat, attlmu, attrmu, attlls, attrls, alc, arc);
    edge23_k<<<nblocks, 256, 0, stream>>>(hcat, alc, arc, offsets, srcs, bmu, bls, out);
}

// Round 3
// 434.882 us; speedup vs baseline: 1.4017x; 1.2069x over previous
//
#include <hip/hip_runtime.h>
#include <math.h>

#define N_NODES 50000
#define N_EDGES 800000
#define ETOT    (N_EDGES + N_NODES)
#define SCAN_BLOCKS ((N_NODES + 255) / 256)   // 196

// ---------------------------------------------------------------- CSR build

__global__ void hist_k(const int* __restrict__ ei, int* __restrict__ counts) {
    int e = blockIdx.x * blockDim.x + threadIdx.x;
    if (e >= ETOT) return;
    int d = (e < N_EDGES) ? ei[N_EDGES + e] : (e - N_EDGES);
    atomicAdd(&counts[d], 1);
}

// per-block reduce of 256-element chunks of counts -> blockSums
__global__ void __launch_bounds__(256) reduce_k(const int* __restrict__ counts,
                                                int* __restrict__ blockSums) {
    __shared__ int red[256];
    int t = threadIdx.x;
    int i = blockIdx.x * 256 + t;
    red[t] = (i < N_NODES) ? counts[i] : 0;
    __syncthreads();
#pragma unroll
    for (int off = 128; off > 0; off >>= 1) {
        if (t < off) red[t] += red[t + off];
        __syncthreads();
    }
    if (t == 0) blockSums[blockIdx.x] = red[0];
}

// single small block: exclusive scan of blockSums (196 entries)
__global__ void __launch_bounds__(256) scansums_k(int* __restrict__ blockSums,
                                                  int* __restrict__ blockBase) {
    __shared__ int s[256];
    int t = threadIdx.x;
    int v = (t < SCAN_BLOCKS) ? blockSums[t] : 0;
    s[t] = v;
    __syncthreads();
#pragma unroll
    for (int off = 1; off < 256; off <<= 1) {
        int u = (t >= off) ? s[t - off] : 0;
        __syncthreads();
        s[t] += u;
        __syncthreads();
    }
    if (t < SCAN_BLOCKS) blockBase[t] = s[t] - v;   // exclusive
}

// per-block exclusive scan of counts chunk + blockBase -> offsets
__global__ void __launch_bounds__(256) scanblk_k(const int* __restrict__ counts,
                                                 const int* __restrict__ blockBase,
                                                 int* __restrict__ offsets) {
    __shared__ int s[256];
    int t = threadIdx.x;
    int i = blockIdx.x * 256 + t;
    int v = (i < N_NODES) ? counts[i] : 0;
    s[t] = v;
    __syncthreads();
#pragma unroll
    for (int off = 1; off < 256; off <<= 1) {
        int u = (t >= off) ? s[t - off] : 0;
        __syncthreads();
        s[t] += u;
        __syncthreads();
    }
    int base = blockBase[blockIdx.x];
    int incl = base + s[t];
    if (i < N_NODES) offsets[i] = incl - v;
    if (i == N_NODES - 1) offsets[N_NODES] = incl;
}

__global__ void scatter_k(const int* __restrict__ ei, const int* __restrict__ offsets,
                          int* __restrict__ fill, int* __restrict__ srcs) {
    int e = blockIdx.x * blockDim.x + threadIdx.x;
    if (e >= ETOT) return;
    int s, d;
    if (e < N_EDGES) { s = ei[e]; d = ei[N_EDGES + e]; }
    else             { s = e - N_EDGES; d = s; }
    int pos = offsets[d] + atomicAdd(&fill[d], 1);
    srcs[pos] = s;
}

// ---------------------------------------------------------------- GEMM  (K=128, NCOL=128; B staged in LDS)

__global__ void __launch_bounds__(256) gemm128_k(const float* __restrict__ A,
                                                 const float* __restrict__ B0,
                                                 const float* __restrict__ B1,
                                                 float* __restrict__ C, int M) {
    __shared__ float Blds[128 * 128];
    __shared__ float Alds[8 * 128];
    int t = threadIdx.x;

    for (int q = t; q < 128 * 32; q += 256) {
        int row = q >> 5, cs = q & 31;
        float4 v;
        if (B1 == nullptr) {
            v = ((const float4*)B0)[row * 32 + cs];
        } else {
            if (cs < 16) v = ((const float4*)B0)[row * 16 + cs];
            else         v = ((const float4*)B1)[row * 16 + (cs - 16)];
        }
        ((float4*)Blds)[q] = v;
    }
    __syncthreads();

    int row = t >> 5, cg = t & 31;
    int tiles = M / 8;
    for (int tile = blockIdx.x; tile < tiles; tile += gridDim.x) {
        int r0 = tile * 8;
        ((float4*)Alds)[t] = ((const float4*)A)[r0 * 32 + t];
        __syncthreads();
        float4 acc = make_float4(0.f, 0.f, 0.f, 0.f);
        const float* arow = &Alds[row * 128];
#pragma unroll 8
        for (int k = 0; k < 128; ++k) {
            float a = arow[k];
            float4 b = ((float4*)Blds)[k * 32 + cg];
            acc.x += a * b.x; acc.y += a * b.y; acc.z += a * b.z; acc.w += a * b.w;
        }
        ((float4*)C)[(r0 + row) * 32 + cg] = acc;
        __syncthreads();
    }
}

// ---------------------------------------------------------------- attention coefficients

__global__ void attn1_k(const float* __restrict__ h, const float* __restrict__ attl,
                        const float* __restrict__ attr, float* __restrict__ al,
                        float* __restrict__ ar) {
    int wid = (blockIdx.x * blockDim.x + threadIdx.x) >> 6;
    int l = threadIdx.x & 63;
    if (wid >= N_NODES) return;
    float2 hv = ((const float2*)(h + (size_t)wid * 128))[l];
    int head = l >> 5;
    float2 alv = ((const float2*)(attl + head * 64))[l & 31];
    float2 arv = ((const float2*)(attr + head * 64))[l & 31];
    float pl = hv.x * alv.x + hv.y * alv.y;
    float pr = hv.x * arv.x + hv.y * arv.y;
#pragma unroll
    for (int m = 1; m < 32; m <<= 1) {
        pl += __shfl_xor(pl, m);
        pr += __shfl_xor(pr, m);
    }
    if ((l & 31) == 0) {
        al[wid * 2 + head] = pl;
        ar[wid * 2 + head] = pr;
    }
}

__global__ void attn23_k(const float* __restrict__ hcat,
                         const float* __restrict__ attlmu, const float* __restrict__ attrmu,
                         const float* __restrict__ attlls, const float* __restrict__ attrls,
                         float* __restrict__ alc, float* __restrict__ arc) {
    int wid = (blockIdx.x * blockDim.x + threadIdx.x) >> 6;
    int l = threadIdx.x & 63;
    if (wid >= N_NODES) return;
    float2 hv = ((const float2*)(hcat + (size_t)wid * 128))[l];
    int g = l >> 4;
    int head = g & 1;
    const float* attl = (l < 32) ? attlmu : attlls;
    const float* attr = (l < 32) ? attrmu : attrls;
    int cpair = l & 15;
    float2 alv = ((const float2*)(attl + head * 32))[cpair];
    float2 arv = ((const float2*)(attr + head * 32))[cpair];
    float pl = hv.x * alv.x + hv.y * alv.y;
    float pr = hv.x * arv.x + hv.y * arv.y;
#pragma unroll
    for (int m = 1; m < 16; m <<= 1) {
        pl += __shfl_xor(pl, m);
        pr += __shfl_xor(pr, m);
    }
    if ((l & 15) == 0) {
        alc[wid * 4 + g] = pl;
        arc[wid * 4 + g] = pr;
    }
}

// ---------------------------------------------------------------- edge aggregation

__device__ __forceinline__ float sigmoidf_fast(float x) {
    return 1.f / (1.f + __expf(-x));
}

// layer 1: wave per dst node, TWO edges per iteration (half-wave each),
// software-pipelined: next edge's j/hj/al are issued before current compute.
__global__ void __launch_bounds__(256) edge1_k(const float* __restrict__ h1,
                                               const float* __restrict__ al,
                                               const float* __restrict__ ar,
                                               const int* __restrict__ offsets,
                                               const int* __restrict__ srcs,
                                               const float* __restrict__ b1,
                                               float* __restrict__ h2) {
    int i = (blockIdx.x * blockDim.x + threadIdx.x) >> 6;
    int l = threadIdx.x & 63;
    if (i >= N_NODES) return;
    int slot = l & 31;          // float4 slot within 128-float row
    int head = (l >> 4) & 1;
    int sub = l >> 5;           // which of the two edges this half-wave handles
    float4 hi = ((const float4*)(h1 + (size_t)i * 128))[slot];
    float ari = ar[i * 2 + head];
    int start = offsets[i], end = offsets[i + 1];
    float s = 0.f;
    float4 o = make_float4(0.f, 0.f, 0.f, 0.f);

    int p = start + sub;
    bool valid = (p < end);
    int j = srcs[valid ? p : start];
    float4 hj = ((const float4*)(h1 + (size_t)j * 128))[slot];
    float alj = al[j * 2 + head];

    for (int pb = start; pb < end; pb += 2) {
        float4 hjc = hj;
        float aljc = alj;
        bool vc = valid;
        // prefetch next
        p += 2;
        valid = (p < end);
        int jn = srcs[valid ? p : start];
        hj = ((const float4*)(h1 + (size_t)jn * 128))[slot];
        alj = al[jn * 2 + head];
        // compute current
        float part = hi.x * hjc.x + hi.y * hjc.y + hi.z * hjc.z + hi.w * hjc.w;
        part += __shfl_xor(part, 1);
        part += __shfl_xor(part, 2);
        part += __shfl_xor(part, 4);
        part += __shfl_xor(part, 8);
        float a = (aljc + ari) * sigmoidf_fast(part);
        a = (a > 0.f) ? a : 0.2f * a;
        a = fminf(a, 60.f);
        float w = vc ? __expf(a) : 0.f;
        s += w;
        o.x += w * hjc.x; o.y += w * hjc.y; o.z += w * hjc.z; o.w += w * hjc.w;
    }
    s   += __shfl_xor(s, 32);
    o.x += __shfl_xor(o.x, 32);
    o.y += __shfl_xor(o.y, 32);
    o.z += __shfl_xor(o.z, 32);
    o.w += __shfl_xor(o.w, 32);
    if (l < 32) {
        float inv = 1.f / (s + 1e-16f);
        float4 bv = ((const float4*)b1)[slot];
        float4 r;
        r.x = o.x * inv + bv.x;
        r.y = o.y * inv + bv.y;
        r.z = o.z * inv + bv.z;
        r.w = o.w * inv + bv.w;
        r.x = (r.x > 0.f) ? r.x : (__expf(r.x) - 1.f);
        r.y = (r.y > 0.f) ? r.y : (__expf(r.y) - 1.f);
        r.z = (r.z > 0.f) ? r.z : (__expf(r.z) - 1.f);
        r.w = (r.w > 0.f) ? r.w : (__expf(r.w) - 1.f);
        ((float4*)(h2 + (size_t)i * 128))[slot] = r;
    }
}

// layers 2+3 fused: wave per dst node, TWO edges per iteration, pipelined.
// 8 lanes x float4 per (branch,head) group covering [mu h0 | mu h1 | ls h0 | ls h1].
__global__ void __launch_bounds__(256) edge23_k(const float* __restrict__ hcat,
                                                const float* __restrict__ alc,
                                                const float* __restrict__ arc,
                                                const int* __restrict__ offsets,
                                                const int* __restrict__ srcs,
                                                const float* __restrict__ bmu,
                                                const float* __restrict__ bls,
                                                float* __restrict__ out) {
    int i = (blockIdx.x * blockDim.x + threadIdx.x) >> 6;
    int l = threadIdx.x & 63;
    if (i >= N_NODES) return;
    int slot = l & 31;
    int g = (l >> 3) & 3;       // 0=mu-h0, 1=mu-h1, 2=ls-h0, 3=ls-h1
    int sub = l >> 5;
    float4 hi = ((const float4*)(hcat + (size_t)i * 128))[slot];
    float ari = arc[i * 4 + g];
    int start = offsets[i], end = offsets[i + 1];
    float s = 0.f;
    float4 o = make_float4(0.f, 0.f, 0.f, 0.f);

    int p = start + sub;
    bool valid = (p < end);
    int j = srcs[valid ? p : start];
    float4 hj = ((const float4*)(hcat + (size_t)j * 128))[slot];
    float alj = alc[j * 4 + g];

    for (int pb = start; pb < end; pb += 2) {
        float4 hjc = hj;
        float aljc = alj;
        bool vc = valid;
        p += 2;
        valid = (p < end);
        int jn = srcs[valid ? p : start];
        hj = ((const float4*)(hcat + (size_t)jn * 128))[slot];
        alj = alc[jn * 4 + g];
        float part = hi.x * hjc.x + hi.y * hjc.y + hi.z * hjc.z + hi.w * hjc.w;
        part += __shfl_xor(part, 1);
        part += __shfl_xor(part, 2);
        part += __shfl_xor(part, 4);
        float a = (aljc + ari) * sigmoidf_fast(part);
        a = (a > 0.f) ? a : 0.2f * a;
        a = fminf(a, 60.f);
        float w = vc ? __expf(a) : 0.f;
        s += w;
        o.x += w * hjc.x; o.y += w * hjc.y; o.z += w * hjc.z; o.w += w * hjc.w;
    }
    s   += __shfl_xor(s, 32);
    o.x += __shfl_xor(o.x, 32);
    o.y += __shfl_xor(o.y, 32);
    o.z += __shfl_xor(o.z, 32);
    o.w += __shfl_xor(o.w, 32);
    if (l < 32) {
        float inv = 1.f / (s + 1e-16f);
        int br = (l >> 4) & 1;
        int e4 = l & 15;
        const float* b = br ? bls : bmu;
        float4 bv = ((const float4*)b)[e4];
        float4 r;
        r.x = o.x * inv + bv.x;
        r.y = o.y * inv + bv.y;
        r.z = o.z * inv + bv.z;
        r.w = o.w * inv + bv.w;
        ((float4*)(out + (size_t)br * (N_NODES * 64)))[(size_t)i * 16 + e4] = r;
    }
}

// ---------------------------------------------------------------- launcher

extern "C" void kernel_launch(void* const* d_in, const int* in_sizes, int n_in,
                              void* d_out, int out_size, void* d_ws, size_t ws_size,
                              hipStream_t stream) {
    const float* x      = (const float*)d_in[0];
    const int*   ei     = (const int*)d_in[1];
    const float* W1     = (const float*)d_in[2];
    const float* att_l1 = (const float*)d_in[3];
    const float* att_r1 = (const float*)d_in[4];
    const float* b1     = (const float*)d_in[5];
    const float* Wmu    = (const float*)d_in[6];
    const float* attlmu = (const float*)d_in[7];
    const float* attrmu = (const float*)d_in[8];
    const float* bmu    = (const float*)d_in[9];
    const float* Wls    = (const float*)d_in[10];
    const float* attlls = (const float*)d_in[11];
    const float* attrls = (const float*)d_in[12];
    const float* bls    = (const float*)d_in[13];
    float* out = (float*)d_out;

    float* h1pre = (float*)d_ws;              // 6,400,000
    float* h2    = h1pre + 6400000;           // 6,400,000
    float* hcat  = h2 + 6400000;              // 6,400,000
    float* al1   = hcat + 6400000;            // 100,000
    float* ar1   = al1 + 100000;              // 100,000
    float* alc   = ar1 + 100000;              // 200,000
    float* arc   = alc + 200000;              // 200,000
    int* counts  = (int*)(arc + 200000);      // 50,000
    int* fill    = counts + 50000;            // 50,000
    int* offsets = fill + 50000;              // 50,016
    int* srcs    = offsets + 50016;           // 850,000
    int* bsums   = srcs + 850000;             // 256
    int* bbase   = bsums + 256;               // 256

    hipMemsetAsync(counts, 0, 50000 * sizeof(int), stream);
    hipMemsetAsync(fill, 0, 50000 * sizeof(int), stream);

    int ethreads = 256;
    int eblocks = (ETOT + ethreads - 1) / ethreads;
    hist_k<<<eblocks, ethreads, 0, stream>>>(ei, counts);
    reduce_k<<<SCAN_BLOCKS, 256, 0, stream>>>(counts, bsums);
    scansums_k<<<1, 256, 0, stream>>>(bsums, bbase);
    scanblk_k<<<SCAN_BLOCKS, 256, 0, stream>>>(counts, bbase, offsets);
    scatter_k<<<eblocks, ethreads, 0, stream>>>(ei, offsets, fill, srcs);

    gemm128_k<<<512, 256, 0, stream>>>(x, W1, nullptr, h1pre, N_NODES);

    int nblocks = (N_NODES + 3) / 4;
    attn1_k<<<nblocks, 256, 0, stream>>>(h1pre, att_l1, att_r1, al1, ar1);
    edge1_k<<<nblocks, 256, 0, stream>>>(h1pre, al1, ar1, offsets, srcs, b1, h2);

    gemm128_k<<<512, 256, 0, stream>>>(h2, Wmu, Wls, hcat, N_NODES);
    attn23_k<<<nblocks, 256, 0, stream>>>(hcat, attlmu, attrmu, attlls, attrls, alc, arc);
    edge23_k<<<nblocks, 256, 0, stream>>>(hcat, alc, arc, offsets, srcs, bmu, bls, out);
}

// Round 4
// 370.652 us; speedup vs baseline: 1.6445x; 1.1733x over previous
//
#include <hip/hip_runtime.h>
#include <math.h>

#define N_NODES 50000
#define N_EDGES 800000
#define ETOT    (N_EDGES + N_NODES)
#define SCAN_BLOCKS ((N_NODES + 255) / 256)   // 196

typedef _Float16 half8  __attribute__((ext_vector_type(8)));   // 16 B
typedef _Float16 half4v __attribute__((ext_vector_type(4)));   // 8 B

// ---------------------------------------------------------------- CSR build

__global__ void hist_k(const int* __restrict__ ei, int* __restrict__ counts) {
    int e = blockIdx.x * blockDim.x + threadIdx.x;
    if (e >= ETOT) return;
    int d = (e < N_EDGES) ? ei[N_EDGES + e] : (e - N_EDGES);
    atomicAdd(&counts[d], 1);
}

__global__ void __launch_bounds__(256) reduce_k(const int* __restrict__ counts,
                                                int* __restrict__ blockSums) {
    __shared__ int red[256];
    int t = threadIdx.x;
    int i = blockIdx.x * 256 + t;
    red[t] = (i < N_NODES) ? counts[i] : 0;
    __syncthreads();
#pragma unroll
    for (int off = 128; off > 0; off >>= 1) {
        if (t < off) red[t] += red[t + off];
        __syncthreads();
    }
    if (t == 0) blockSums[blockIdx.x] = red[0];
}

__global__ void __launch_bounds__(256) scansums_k(int* __restrict__ blockSums,
                                                  int* __restrict__ blockBase) {
    __shared__ int s[256];
    int t = threadIdx.x;
    int v = (t < SCAN_BLOCKS) ? blockSums[t] : 0;
    s[t] = v;
    __syncthreads();
#pragma unroll
    for (int off = 1; off < 256; off <<= 1) {
        int u = (t >= off) ? s[t - off] : 0;
        __syncthreads();
        s[t] += u;
        __syncthreads();
    }
    if (t < SCAN_BLOCKS) blockBase[t] = s[t] - v;
}

__global__ void __launch_bounds__(256) scanblk_k(const int* __restrict__ counts,
                                                 const int* __restrict__ blockBase,
                                                 int* __restrict__ offsets) {
    __shared__ int s[256];
    int t = threadIdx.x;
    int i = blockIdx.x * 256 + t;
    int v = (i < N_NODES) ? counts[i] : 0;
    s[t] = v;
    __syncthreads();
#pragma unroll
    for (int off = 1; off < 256; off <<= 1) {
        int u = (t >= off) ? s[t - off] : 0;
        __syncthreads();
        s[t] += u;
        __syncthreads();
    }
    int base = blockBase[blockIdx.x];
    int incl = base + s[t];
    if (i < N_NODES) offsets[i] = incl - v;
    if (i == N_NODES - 1) offsets[N_NODES] = incl;
}

__global__ void scatter_k(const int* __restrict__ ei, const int* __restrict__ offsets,
                          int* __restrict__ fill, int* __restrict__ srcs) {
    int e = blockIdx.x * blockDim.x + threadIdx.x;
    if (e >= ETOT) return;
    int s, d;
    if (e < N_EDGES) { s = ei[e]; d = ei[N_EDGES + e]; }
    else             { s = e - N_EDGES; d = s; }
    int pos = offsets[d] + atomicAdd(&fill[d], 1);
    srcs[pos] = s;
}

// ---------------------------------------------------------------- GEMMs (K=128, NCOL=128, fp16 C)

__global__ void __launch_bounds__(256) gemm_f32A_k(const float* __restrict__ A,
                                                   const float* __restrict__ B0,
                                                   const float* __restrict__ B1,
                                                   _Float16* __restrict__ C, int M) {
    __shared__ float Blds[128 * 128];
    __shared__ float Alds[8 * 128];
    int t = threadIdx.x;
    for (int qq = t; qq < 128 * 32; qq += 256) {
        int row = qq >> 5, cs = qq & 31;
        float4 v;
        if (B1 == nullptr) v = ((const float4*)B0)[row * 32 + cs];
        else v = (cs < 16) ? ((const float4*)B0)[row * 16 + cs]
                           : ((const float4*)B1)[row * 16 + (cs - 16)];
        ((float4*)Blds)[qq] = v;
    }
    __syncthreads();
    int row = t >> 5, cg = t & 31;
    int tiles = M / 8;
    for (int tile = blockIdx.x; tile < tiles; tile += gridDim.x) {
        int r0 = tile * 8;
        ((float4*)Alds)[t] = ((const float4*)A)[r0 * 32 + t];
        __syncthreads();
        float4 acc = make_float4(0.f, 0.f, 0.f, 0.f);
        const float* arow = &Alds[row * 128];
#pragma unroll 8
        for (int k = 0; k < 128; ++k) {
            float a = arow[k];
            float4 b = ((float4*)Blds)[k * 32 + cg];
            acc.x += a * b.x; acc.y += a * b.y; acc.z += a * b.z; acc.w += a * b.w;
        }
        half4v r;
        r[0] = (_Float16)acc.x; r[1] = (_Float16)acc.y;
        r[2] = (_Float16)acc.z; r[3] = (_Float16)acc.w;
        ((half4v*)C)[(r0 + row) * 32 + cg] = r;
        __syncthreads();
    }
}

__global__ void __launch_bounds__(256) gemm_f16A_k(const _Float16* __restrict__ A,
                                                   const float* __restrict__ B0,
                                                   const float* __restrict__ B1,
                                                   _Float16* __restrict__ C, int M) {
    __shared__ float Blds[128 * 128];
    __shared__ float Alds[8 * 128];
    int t = threadIdx.x;
    for (int qq = t; qq < 128 * 32; qq += 256) {
        int row = qq >> 5, cs = qq & 31;
        float4 v;
        if (B1 == nullptr) v = ((const float4*)B0)[row * 32 + cs];
        else v = (cs < 16) ? ((const float4*)B0)[row * 16 + cs]
                           : ((const float4*)B1)[row * 16 + (cs - 16)];
        ((float4*)Blds)[qq] = v;
    }
    __syncthreads();
    int row = t >> 5, cg = t & 31;
    int tiles = M / 8;
    for (int tile = blockIdx.x; tile < tiles; tile += gridDim.x) {
        int r0 = tile * 8;
        half4v ah = ((const half4v*)A)[r0 * 32 + t];
        float4 av;
        av.x = (float)ah[0]; av.y = (float)ah[1]; av.z = (float)ah[2]; av.w = (float)ah[3];
        ((float4*)Alds)[t] = av;
        __syncthreads();
        float4 acc = make_float4(0.f, 0.f, 0.f, 0.f);
        const float* arow = &Alds[row * 128];
#pragma unroll 8
        for (int k = 0; k < 128; ++k) {
            float a = arow[k];
            float4 b = ((float4*)Blds)[k * 32 + cg];
            acc.x += a * b.x; acc.y += a * b.y; acc.z += a * b.z; acc.w += a * b.w;
        }
        half4v r;
        r[0] = (_Float16)acc.x; r[1] = (_Float16)acc.y;
        r[2] = (_Float16)acc.z; r[3] = (_Float16)acc.w;
        ((half4v*)C)[(r0 + row) * 32 + cg] = r;
        __syncthreads();
    }
}

// ---------------------------------------------------------------- attention coefficients (fp16 h, 2 nodes/wave)

__global__ void attn1_k(const _Float16* __restrict__ h, const float* __restrict__ attl,
                        const float* __restrict__ attr, float* __restrict__ al,
                        float* __restrict__ ar) {
    int wid = (blockIdx.x * blockDim.x + threadIdx.x) >> 6;
    int l = threadIdx.x & 63;
    int i = wid * 2 + (l >> 5);
    if (i >= N_NODES) return;
    int m = l & 31;
    int head = m >> 4;
    half4v hv = ((const half4v*)(h + (size_t)i * 128))[m];
    float4 alv = ((const float4*)(attl + head * 64))[m & 15];
    float4 arv = ((const float4*)(attr + head * 64))[m & 15];
    float h0 = (float)hv[0], h1f = (float)hv[1], h2f = (float)hv[2], h3f = (float)hv[3];
    float pl = h0 * alv.x + h1f * alv.y + h2f * alv.z + h3f * alv.w;
    float pr = h0 * arv.x + h1f * arv.y + h2f * arv.z + h3f * arv.w;
#pragma unroll
    for (int mm = 1; mm < 16; mm <<= 1) {
        pl += __shfl_xor(pl, mm);
        pr += __shfl_xor(pr, mm);
    }
    if ((m & 15) == 0) {
        al[i * 2 + head] = pl;
        ar[i * 2 + head] = pr;
    }
}

__global__ void attn23_k(const _Float16* __restrict__ hcat,
                         const float* __restrict__ attlmu, const float* __restrict__ attrmu,
                         const float* __restrict__ attlls, const float* __restrict__ attrls,
                         float* __restrict__ alc, float* __restrict__ arc) {
    int wid = (blockIdx.x * blockDim.x + threadIdx.x) >> 6;
    int l = threadIdx.x & 63;
    int i = wid * 2 + (l >> 5);
    if (i >= N_NODES) return;
    int m = l & 31;
    int g = m >> 3;             // 0=mu-h0, 1=mu-h1, 2=ls-h0, 3=ls-h1
    int head = g & 1;
    int br = g >> 1;
    half4v hv = ((const half4v*)(hcat + (size_t)i * 128))[m];
    const float* attl = br ? attlls : attlmu;
    const float* attr = br ? attrls : attrmu;
    float4 alv = ((const float4*)(attl + head * 32))[m & 7];
    float4 arv = ((const float4*)(attr + head * 32))[m & 7];
    float h0 = (float)hv[0], h1f = (float)hv[1], h2f = (float)hv[2], h3f = (float)hv[3];
    float pl = h0 * alv.x + h1f * alv.y + h2f * alv.z + h3f * alv.w;
    float pr = h0 * arv.x + h1f * arv.y + h2f * arv.z + h3f * arv.w;
#pragma unroll
    for (int mm = 1; mm < 8; mm <<= 1) {
        pl += __shfl_xor(pl, mm);
        pr += __shfl_xor(pr, mm);
    }
    if ((m & 7) == 0) {
        alc[i * 4 + g] = pl;
        arc[i * 4 + g] = pr;
    }
}

// ---------------------------------------------------------------- edge aggregation (fp16 gather, 4 edges/wave, 3-deep prefetch)

__device__ __forceinline__ float sigmoidf_fast(float x) {
    return 1.f / (1.f + __expf(-x));
}

// layer 1: wave per dst node, quarter-wave (16 lanes x half8) per edge.
__global__ void __launch_bounds__(256) edge1_k(const _Float16* __restrict__ h1,
                                               const float* __restrict__ al,
                                               const float* __restrict__ ar,
                                               const int* __restrict__ offsets,
                                               const int* __restrict__ srcs,
                                               const float* __restrict__ b1,
                                               _Float16* __restrict__ h2) {
    int i = (blockIdx.x * blockDim.x + threadIdx.x) >> 6;
    int l = threadIdx.x & 63;
    if (i >= N_NODES) return;
    int q = l & 15;             // half8 slot within 128-half row
    int head = q >> 3;
    int sub = l >> 4;           // 0..3: which edge of the quad

    half8 hi8 = ((const half8*)(h1 + (size_t)i * 128))[q];
    float hi0 = (float)hi8[0], hi1 = (float)hi8[1], hi2 = (float)hi8[2], hi3 = (float)hi8[3];
    float hi4 = (float)hi8[4], hi5 = (float)hi8[5], hi6 = (float)hi8[6], hi7 = (float)hi8[7];
    float ari = ar[i * 2 + head];
    int start = offsets[i], end = offsets[i + 1];
    float s = 0.f;
    float o0 = 0.f, o1 = 0.f, o2 = 0.f, o3 = 0.f, o4 = 0.f, o5 = 0.f, o6 = 0.f, o7 = 0.f;

    // 3-deep pipeline, stride 4
    int p0 = start + sub, p1 = p0 + 4, p2 = p0 + 8;
    bool v0 = p0 < end, v1 = p1 < end, v2 = p2 < end;
    int j0 = srcs[v0 ? p0 : start];
    int j1 = srcs[v1 ? p1 : start];
    int j2 = srcs[v2 ? p2 : start];
    half8 q0 = ((const half8*)(h1 + (size_t)j0 * 128))[q];
    half8 q1 = ((const half8*)(h1 + (size_t)j1 * 128))[q];
    half8 q2 = ((const half8*)(h1 + (size_t)j2 * 128))[q];
    float a0 = al[j0 * 2 + head];
    float a1 = al[j1 * 2 + head];
    float a2 = al[j2 * 2 + head];

    for (int pb = start; pb < end; pb += 4) {
        half8 hc = q0; float ac = a0; bool vc = v0;
        q0 = q1; a0 = a1; v0 = v1;
        q1 = q2; a1 = a2; v1 = v2;
        p2 += 4;
        v2 = p2 < end;
        int jn = srcs[v2 ? p2 : start];
        q2 = ((const half8*)(h1 + (size_t)jn * 128))[q];
        a2 = al[jn * 2 + head];

        float f0 = (float)hc[0], f1 = (float)hc[1], f2 = (float)hc[2], f3 = (float)hc[3];
        float f4 = (float)hc[4], f5 = (float)hc[5], f6 = (float)hc[6], f7 = (float)hc[7];
        float part = hi0 * f0 + hi1 * f1 + hi2 * f2 + hi3 * f3
                   + hi4 * f4 + hi5 * f5 + hi6 * f6 + hi7 * f7;
        part += __shfl_xor(part, 1);
        part += __shfl_xor(part, 2);
        part += __shfl_xor(part, 4);
        float a = (ac + ari) * sigmoidf_fast(part);
        a = (a > 0.f) ? a : 0.2f * a;
        a = fminf(a, 60.f);
        float w = vc ? __expf(a) : 0.f;
        s += w;
        o0 += w * f0; o1 += w * f1; o2 += w * f2; o3 += w * f3;
        o4 += w * f4; o5 += w * f5; o6 += w * f6; o7 += w * f7;
    }
    // merge the 4 sub-wave accumulators
    s  += __shfl_xor(s, 16);  s  += __shfl_xor(s, 32);
    o0 += __shfl_xor(o0, 16); o0 += __shfl_xor(o0, 32);
    o1 += __shfl_xor(o1, 16); o1 += __shfl_xor(o1, 32);
    o2 += __shfl_xor(o2, 16); o2 += __shfl_xor(o2, 32);
    o3 += __shfl_xor(o3, 16); o3 += __shfl_xor(o3, 32);
    o4 += __shfl_xor(o4, 16); o4 += __shfl_xor(o4, 32);
    o5 += __shfl_xor(o5, 16); o5 += __shfl_xor(o5, 32);
    o6 += __shfl_xor(o6, 16); o6 += __shfl_xor(o6, 32);
    o7 += __shfl_xor(o7, 16); o7 += __shfl_xor(o7, 32);
    if (l < 16) {
        float inv = 1.f / (s + 1e-16f);
        float4 bva = ((const float4*)b1)[l * 2];
        float4 bvb = ((const float4*)b1)[l * 2 + 1];
        float r0 = o0 * inv + bva.x, r1 = o1 * inv + bva.y;
        float r2 = o2 * inv + bva.z, r3 = o3 * inv + bva.w;
        float r4 = o4 * inv + bvb.x, r5 = o5 * inv + bvb.y;
        float r6 = o6 * inv + bvb.z, r7 = o7 * inv + bvb.w;
        r0 = (r0 > 0.f) ? r0 : (__expf(r0) - 1.f);
        r1 = (r1 > 0.f) ? r1 : (__expf(r1) - 1.f);
        r2 = (r2 > 0.f) ? r2 : (__expf(r2) - 1.f);
        r3 = (r3 > 0.f) ? r3 : (__expf(r3) - 1.f);
        r4 = (r4 > 0.f) ? r4 : (__expf(r4) - 1.f);
        r5 = (r5 > 0.f) ? r5 : (__expf(r5) - 1.f);
        r6 = (r6 > 0.f) ? r6 : (__expf(r6) - 1.f);
        r7 = (r7 > 0.f) ? r7 : (__expf(r7) - 1.f);
        half8 r;
        r[0] = (_Float16)r0; r[1] = (_Float16)r1; r[2] = (_Float16)r2; r[3] = (_Float16)r3;
        r[4] = (_Float16)r4; r[5] = (_Float16)r5; r[6] = (_Float16)r6; r[7] = (_Float16)r7;
        ((half8*)(h2 + (size_t)i * 128))[l] = r;
    }
}

// layers 2+3 fused: wave per dst node, quarter-wave per edge; 4-lane (branch,head)
// groups over hcat row = [mu h0 | mu h1 | ls h0 | ls h1]. Writes d_out (fp32).
__global__ void __launch_bounds__(256) edge23_k(const _Float16* __restrict__ hcat,
                                                const float* __restrict__ alc,
                                                const float* __restrict__ arc,
                                                const int* __restrict__ offsets,
                                                const int* __restrict__ srcs,
                                                const float* __restrict__ bmu,
                                                const float* __restrict__ bls,
                                                float* __restrict__ out) {
    int i = (blockIdx.x * blockDim.x + threadIdx.x) >> 6;
    int l = threadIdx.x & 63;
    if (i >= N_NODES) return;
    int q = l & 15;
    int g = (l >> 2) & 3;       // 32-ch group of this lane's channels
    int sub = l >> 4;

    half8 hi8 = ((const half8*)(hcat + (size_t)i * 128))[q];
    float hi0 = (float)hi8[0], hi1 = (float)hi8[1], hi2 = (float)hi8[2], hi3 = (float)hi8[3];
    float hi4 = (float)hi8[4], hi5 = (float)hi8[5], hi6 = (float)hi8[6], hi7 = (float)hi8[7];
    float ari = arc[i * 4 + g];
    int start = offsets[i], end = offsets[i + 1];
    float s = 0.f;
    float o0 = 0.f, o1 = 0.f, o2 = 0.f, o3 = 0.f, o4 = 0.f, o5 = 0.f, o6 = 0.f, o7 = 0.f;

    int p0 = start + sub, p1 = p0 + 4, p2 = p0 + 8;
    bool v0 = p0 < end, v1 = p1 < end, v2 = p2 < end;
    int j0 = srcs[v0 ? p0 : start];
    int j1 = srcs[v1 ? p1 : start];
    int j2 = srcs[v2 ? p2 : start];
    half8 q0 = ((const half8*)(hcat + (size_t)j0 * 128))[q];
    half8 q1 = ((const half8*)(hcat + (size_t)j1 * 128))[q];
    half8 q2 = ((const half8*)(hcat + (size_t)j2 * 128))[q];
    float a0 = alc[j0 * 4 + g];
    float a1 = alc[j1 * 4 + g];
    float a2 = alc[j2 * 4 + g];

    for (int pb = start; pb < end; pb += 4) {
        half8 hc = q0; float ac = a0; bool vc = v0;
        q0 = q1; a0 = a1; v0 = v1;
        q1 = q2; a1 = a2; v1 = v2;
        p2 += 4;
        v2 = p2 < end;
        int jn = srcs[v2 ? p2 : start];
        q2 = ((const half8*)(hcat + (size_t)jn * 128))[q];
        a2 = alc[jn * 4 + g];

        float f0 = (float)hc[0], f1 = (float)hc[1], f2 = (float)hc[2], f3 = (float)hc[3];
        float f4 = (float)hc[4], f5 = (float)hc[5], f6 = (float)hc[6], f7 = (float)hc[7];
        float part = hi0 * f0 + hi1 * f1 + hi2 * f2 + hi3 * f3
                   + hi4 * f4 + hi5 * f5 + hi6 * f6 + hi7 * f7;
        part += __shfl_xor(part, 1);
        part += __shfl_xor(part, 2);
        float a = (ac + ari) * sigmoidf_fast(part);
        a = (a > 0.f) ? a : 0.2f * a;
        a = fminf(a, 60.f);
        float w = vc ? __expf(a) : 0.f;
        s += w;
        o0 += w * f0; o1 += w * f1; o2 += w * f2; o3 += w * f3;
        o4 += w * f4; o5 += w * f5; o6 += w * f6; o7 += w * f7;
    }
    s  += __shfl_xor(s, 16);  s  += __shfl_xor(s, 32);
    o0 += __shfl_xor(o0, 16); o0 += __shfl_xor(o0, 32);
    o1 += __shfl_xor(o1, 16); o1 += __shfl_xor(o1, 32);
    o2 += __shfl_xor(o2, 16); o2 += __shfl_xor(o2, 32);
    o3 += __shfl_xor(o3, 16); o3 += __shfl_xor(o3, 32);
    o4 += __shfl_xor(o4, 16); o4 += __shfl_xor(o4, 32);
    o5 += __shfl_xor(o5, 16); o5 += __shfl_xor(o5, 32);
    o6 += __shfl_xor(o6, 16); o6 += __shfl_xor(o6, 32);
    o7 += __shfl_xor(o7, 16); o7 += __shfl_xor(o7, 32);
    if (l < 16) {
        float inv = 1.f / (s + 1e-16f);
        int br = l >> 3;                    // 0 = mu, 1 = logstd
        int c0 = 8 * (l & 7);               // channel within 64-ch branch row
        const float* b = br ? bls : bmu;
        float4 bva = ((const float4*)(b + c0))[0];
        float4 bvb = ((const float4*)(b + c0))[1];
        float4 ra, rb;
        ra.x = o0 * inv + bva.x; ra.y = o1 * inv + bva.y;
        ra.z = o2 * inv + bva.z; ra.w = o3 * inv + bva.w;
        rb.x = o4 * inv + bvb.x; rb.y = o5 * inv + bvb.y;
        rb.z = o6 * inv + bvb.z; rb.w = o7 * inv + bvb.w;
        float* dst = out + (size_t)br * (N_NODES * 64) + (size_t)i * 64 + c0;
        ((float4*)dst)[0] = ra;
        ((float4*)dst)[1] = rb;
    }
}

// ---------------------------------------------------------------- launcher

extern "C" void kernel_launch(void* const* d_in, const int* in_sizes, int n_in,
                              void* d_out, int out_size, void* d_ws, size_t ws_size,
                              hipStream_t stream) {
    const float* x      = (const float*)d_in[0];
    const int*   ei     = (const int*)d_in[1];
    const float* W1     = (const float*)d_in[2];
    const float* att_l1 = (const float*)d_in[3];
    const float* att_r1 = (const float*)d_in[4];
    const float* b1     = (const float*)d_in[5];
    const float* Wmu    = (const float*)d_in[6];
    const float* attlmu = (const float*)d_in[7];
    const float* attrmu = (const float*)d_in[8];
    const float* bmu    = (const float*)d_in[9];
    const float* Wls    = (const float*)d_in[10];
    const float* attlls = (const float*)d_in[11];
    const float* attrls = (const float*)d_in[12];
    const float* bls    = (const float*)d_in[13];
    float* out = (float*)d_out;

    _Float16* h1   = (_Float16*)d_ws;         // 6,400,000 halfs
    _Float16* h2   = h1 + 6400000;            // 6,400,000 halfs
    _Float16* hcat = h2 + 6400000;            // 6,400,000 halfs
    float* al1   = (float*)(hcat + 6400000);  // 100,000
    float* ar1   = al1 + 100000;              // 100,000
    float* alc   = ar1 + 100000;              // 200,000
    float* arc   = alc + 200000;              // 200,000
    int* counts  = (int*)(arc + 200000);      // 50,000
    int* fill    = counts + 50000;            // 50,000
    int* offsets = fill + 50000;              // 50,016
    int* srcs    = offsets + 50016;           // 850,000
    int* bsums   = srcs + 850000;             // 256
    int* bbase   = bsums + 256;               // 256

    hipMemsetAsync(counts, 0, 50000 * sizeof(int), stream);
    hipMemsetAsync(fill, 0, 50000 * sizeof(int), stream);

    int ethreads = 256;
    int eblocks = (ETOT + ethreads - 1) / ethreads;
    hist_k<<<eblocks, ethreads, 0, stream>>>(ei, counts);
    reduce_k<<<SCAN_BLOCKS, 256, 0, stream>>>(counts, bsums);
    scansums_k<<<1, 256, 0, stream>>>(bsums, bbase);
    scanblk_k<<<SCAN_BLOCKS, 256, 0, stream>>>(counts, bbase, offsets);
    scatter_k<<<eblocks, ethreads, 0, stream>>>(ei, offsets, fill, srcs);

    gemm_f32A_k<<<512, 256, 0, stream>>>(x, W1, nullptr, h1, N_NODES);

    int nblocks = (N_NODES + 3) / 4;       // edge kernels: 4 waves (nodes) / block
    int ablocks = (N_NODES + 7) / 8;       // attn kernels: 2 nodes / wave
    attn1_k<<<ablocks, 256, 0, stream>>>(h1, att_l1, att_r1, al1, ar1);
    edge1_k<<<nblocks, 256, 0, stream>>>(h1, al1, ar1, offsets, srcs, b1, h2);

    gemm_f16A_k<<<512, 256, 0, stream>>>(h2, Wmu, Wls, hcat, N_NODES);
    attn23_k<<<ablocks, 256, 0, stream>>>(hcat, attlmu, attrmu, attlls, attrls, alc, arc);
    edge23_k<<<nblocks, 256, 0, stream>>>(hcat, alc, arc, offsets, srcs, bmu, bls, out);
}

// Round 5
// 332.246 us; speedup vs baseline: 1.8347x; 1.1156x over previous
//
#include <hip/hip_runtime.h>
#include <math.h>

#define N_NODES 50000
#define N_EDGES 800000
#define ETOT    (N_EDGES + N_NODES)
#define SCAN_BLOCKS ((N_NODES + 255) / 256)   // 196
#define GEMM_TILES ((N_NODES + 63) / 64)      // 782

typedef _Float16 f16x8 __attribute__((ext_vector_type(8)));   // 16 B
typedef _Float16 f16x4 __attribute__((ext_vector_type(4)));   // 8 B
typedef _Float16 f16x2 __attribute__((ext_vector_type(2)));   // 4 B
typedef float    f32x4 __attribute__((ext_vector_type(4)));

// ---------------------------------------------------------------- CSR build

__global__ void hist_k(const int* __restrict__ ei, int* __restrict__ counts) {
    int e = blockIdx.x * blockDim.x + threadIdx.x;
    if (e >= ETOT) return;
    int d = (e < N_EDGES) ? ei[N_EDGES + e] : (e - N_EDGES);
    atomicAdd(&counts[d], 1);
}

__global__ void __launch_bounds__(256) reduce_k(const int* __restrict__ counts,
                                                int* __restrict__ blockSums) {
    __shared__ int red[256];
    int t = threadIdx.x;
    int i = blockIdx.x * 256 + t;
    red[t] = (i < N_NODES) ? counts[i] : 0;
    __syncthreads();
#pragma unroll
    for (int off = 128; off > 0; off >>= 1) {
        if (t < off) red[t] += red[t + off];
        __syncthreads();
    }
    if (t == 0) blockSums[blockIdx.x] = red[0];
}

__global__ void __launch_bounds__(256) scansums_k(int* __restrict__ blockSums,
                                                  int* __restrict__ blockBase) {
    __shared__ int s[256];
    int t = threadIdx.x;
    int v = (t < SCAN_BLOCKS) ? blockSums[t] : 0;
    s[t] = v;
    __syncthreads();
#pragma unroll
    for (int off = 1; off < 256; off <<= 1) {
        int u = (t >= off) ? s[t - off] : 0;
        __syncthreads();
        s[t] += u;
        __syncthreads();
    }
    if (t < SCAN_BLOCKS) blockBase[t] = s[t] - v;
}

__global__ void __launch_bounds__(256) scanblk_k(const int* __restrict__ counts,
                                                 const int* __restrict__ blockBase,
                                                 int* __restrict__ offsets) {
    __shared__ int s[256];
    int t = threadIdx.x;
    int i = blockIdx.x * 256 + t;
    int v = (i < N_NODES) ? counts[i] : 0;
    s[t] = v;
    __syncthreads();
#pragma unroll
    for (int off = 1; off < 256; off <<= 1) {
        int u = (t >= off) ? s[t - off] : 0;
        __syncthreads();
        s[t] += u;
        __syncthreads();
    }
    int base = blockBase[blockIdx.x];
    int incl = base + s[t];
    if (i < N_NODES) offsets[i] = incl - v;
    if (i == N_NODES - 1) offsets[N_NODES] = incl;
}

__global__ void scatter_k(const int* __restrict__ ei, const int* __restrict__ offsets,
                          int* __restrict__ fill, int* __restrict__ srcs) {
    int e = blockIdx.x * blockDim.x + threadIdx.x;
    if (e >= ETOT) return;
    int s, d;
    if (e < N_EDGES) { s = ei[e]; d = ei[N_EDGES + e]; }
    else             { s = e - N_EDGES; d = s; }
    int pos = offsets[d] + atomicAdd(&fill[d], 1);
    srcs[pos] = s;
}

// ---------------------------------------------------------------- MFMA GEMMs (M x 128 @ 128 x 128, fp16 in MFMA, fp32 acc)
// B is converted+transposed+XOR-swizzled into LDS once per block.
// Bt layout: row n (0..127), 16 granules of 8 halfs; logical k-granule gk
// stored at granule gk ^ (n & 7)  -> conflict-free ds_read_b128 fragments.

__device__ __forceinline__ void stage_B(const float* __restrict__ B0,
                                        const float* __restrict__ B1,
                                        _Float16* Braw, _Float16* Bt, int t) {
    if (B1 == nullptr) {
        for (int it = 0; it < 16; ++it) {
            int id = it * 256 + t;           // 4096 float4
            int k = id >> 5, c4 = id & 31;
            float4 v = ((const float4*)B0)[id];
            _Float16* d = &Braw[k * 128 + c4 * 4];
            d[0] = (_Float16)v.x; d[1] = (_Float16)v.y;
            d[2] = (_Float16)v.z; d[3] = (_Float16)v.w;
        }
    } else {
        for (int it = 0; it < 8; ++it) {
            int id = it * 256 + t;           // 2048 float4 per half-matrix
            int k = id >> 4, c4 = id & 15;
            float4 v = ((const float4*)B0)[id];
            _Float16* d = &Braw[k * 128 + c4 * 4];
            d[0] = (_Float16)v.x; d[1] = (_Float16)v.y;
            d[2] = (_Float16)v.z; d[3] = (_Float16)v.w;
            float4 w = ((const float4*)B1)[id];
            _Float16* e = &Braw[k * 128 + 64 + c4 * 4];
            e[0] = (_Float16)w.x; e[1] = (_Float16)w.y;
            e[2] = (_Float16)w.z; e[3] = (_Float16)w.w;
        }
    }
    __syncthreads();
    for (int it = 0; it < 8; ++it) {
        int id = it * 256 + t;               // 2048 granules
        int n = id >> 4, gk = id & 15;
        f16x8 g;
#pragma unroll
        for (int j = 0; j < 8; ++j) g[j] = Braw[(gk * 8 + j) * 128 + n];
        int gs = gk ^ (n & 7);
        *(f16x8*)&Bt[n * 128 + gs * 8] = g;
    }
    __syncthreads();
}

__device__ __forceinline__ void gemm_core(const f16x8 a[4], const _Float16* Bt,
                                          _Float16* cs, _Float16* __restrict__ C,
                                          int r0, int l) {
    int i16 = l & 15, q = l >> 4;
    f32x4 acc[8];
#pragma unroll
    for (int tt = 0; tt < 8; ++tt) acc[tt] = (f32x4){0.f, 0.f, 0.f, 0.f};
#pragma unroll
    for (int kb = 0; kb < 4; ++kb) {
#pragma unroll
        for (int tt = 0; tt < 8; ++tt) {
            int n = tt * 16 + i16;
            int gs = (kb * 4 + q) ^ (n & 7);
            f16x8 b = *(const f16x8*)&Bt[n * 128 + gs * 8];
            acc[tt] = __builtin_amdgcn_mfma_f32_16x16x32_f16(a[kb], b, acc[tt], 0, 0, 0);
        }
    }
    // acc[tt][r] = D[row = q*4+r][col = tt*16+i16]; stage to LDS, store coalesced
#pragma unroll
    for (int tt = 0; tt < 8; ++tt)
#pragma unroll
        for (int r = 0; r < 4; ++r)
            cs[(q * 4 + r) * 128 + tt * 16 + i16] = (_Float16)acc[tt][r];
#pragma unroll
    for (int u = 0; u < 4; ++u) {
        int idx = u * 64 + l;                // half8 index, 256 total
        int rr = idx >> 4, cc = idx & 15;
        ((f16x8*)(C + (size_t)(r0 + rr) * 128))[cc] = ((f16x8*)cs)[idx];
    }
}

__global__ void __launch_bounds__(256) gemm_mfma_f32A_k(const float* __restrict__ A,
                                                        const float* __restrict__ B0,
                                                        const float* __restrict__ B1,
                                                        _Float16* __restrict__ C, int M) {
    __shared__ _Float16 Braw[128 * 128];
    __shared__ _Float16 Bt[128 * 128];
    __shared__ _Float16 Cst[4][16 * 128];
    int t = threadIdx.x;
    stage_B(B0, B1, Braw, Bt, t);
    int wave = t >> 6, l = t & 63;
    int i16 = l & 15, q = l >> 4;
    for (int tile = blockIdx.x; tile * 64 < M; tile += gridDim.x) {
        int r0 = tile * 64 + wave * 16;
        if (r0 >= M) continue;               // M is a multiple of 16
        const float* ar_ = A + (size_t)(r0 + i16) * 128;
        f16x8 a[4];
#pragma unroll
        for (int kb = 0; kb < 4; ++kb) {
            float4 u = ((const float4*)(ar_ + kb * 32 + q * 8))[0];
            float4 v = ((const float4*)(ar_ + kb * 32 + q * 8))[1];
            f16x8 t8;
            t8[0] = (_Float16)u.x; t8[1] = (_Float16)u.y;
            t8[2] = (_Float16)u.z; t8[3] = (_Float16)u.w;
            t8[4] = (_Float16)v.x; t8[5] = (_Float16)v.y;
            t8[6] = (_Float16)v.z; t8[7] = (_Float16)v.w;
            a[kb] = t8;
        }
        gemm_core(a, Bt, &Cst[wave][0], C, r0, l);
    }
}

__global__ void __launch_bounds__(256) gemm_mfma_f16A_k(const _Float16* __restrict__ A,
                                                        const float* __restrict__ B0,
                                                        const float* __restrict__ B1,
                                                        _Float16* __restrict__ C, int M) {
    __shared__ _Float16 Braw[128 * 128];
    __shared__ _Float16 Bt[128 * 128];
    __shared__ _Float16 Cst[4][16 * 128];
    int t = threadIdx.x;
    stage_B(B0, B1, Braw, Bt, t);
    int wave = t >> 6, l = t & 63;
    int i16 = l & 15, q = l >> 4;
    for (int tile = blockIdx.x; tile * 64 < M; tile += gridDim.x) {
        int r0 = tile * 64 + wave * 16;
        if (r0 >= M) continue;
        const _Float16* ar_ = A + (size_t)(r0 + i16) * 128;
        f16x8 a[4];
#pragma unroll
        for (int kb = 0; kb < 4; ++kb)
            a[kb] = *(const f16x8*)(ar_ + kb * 32 + q * 8);
        gemm_core(a, Bt, &Cst[wave][0], C, r0, l);
    }
}

// ---------------------------------------------------------------- attention coefficients (fp16 h, 2 nodes/wave)

__global__ void attn1_k(const _Float16* __restrict__ h, const float* __restrict__ attl,
                        const float* __restrict__ attr, float* __restrict__ al,
                        float* __restrict__ ar) {
    int wid = (blockIdx.x * blockDim.x + threadIdx.x) >> 6;
    int l = threadIdx.x & 63;
    int i = wid * 2 + (l >> 5);
    if (i >= N_NODES) return;
    int m = l & 31;
    int head = m >> 4;
    f16x4 hv = ((const f16x4*)(h + (size_t)i * 128))[m];
    float4 alv = ((const float4*)(attl + head * 64))[m & 15];
    float4 arv = ((const float4*)(attr + head * 64))[m & 15];
    float h0 = (float)hv[0], h1f = (float)hv[1], h2f = (float)hv[2], h3f = (float)hv[3];
    float pl = h0 * alv.x + h1f * alv.y + h2f * alv.z + h3f * alv.w;
    float pr = h0 * arv.x + h1f * arv.y + h2f * arv.z + h3f * arv.w;
#pragma unroll
    for (int mm = 1; mm < 16; mm <<= 1) {
        pl += __shfl_xor(pl, mm);
        pr += __shfl_xor(pr, mm);
    }
    if ((m & 15) == 0) {
        al[i * 2 + head] = pl;
        ar[i * 2 + head] = pr;
    }
}

__global__ void attn23_k(const _Float16* __restrict__ hcat,
                         const float* __restrict__ attlmu, const float* __restrict__ attrmu,
                         const float* __restrict__ attlls, const float* __restrict__ attrls,
                         float* __restrict__ alc, float* __restrict__ arc) {
    int wid = (blockIdx.x * blockDim.x + threadIdx.x) >> 6;
    int l = threadIdx.x & 63;
    int i = wid * 2 + (l >> 5);
    if (i >= N_NODES) return;
    int m = l & 31;
    int g = m >> 3;
    int head = g & 1;
    int br = g >> 1;
    f16x4 hv = ((const f16x4*)(hcat + (size_t)i * 128))[m];
    const float* attl = br ? attlls : attlmu;
    const float* attr = br ? attrls : attrmu;
    float4 alv = ((const float4*)(attl + head * 32))[m & 7];
    float4 arv = ((const float4*)(attr + head * 32))[m & 7];
    float h0 = (float)hv[0], h1f = (float)hv[1], h2f = (float)hv[2], h3f = (float)hv[3];
    float pl = h0 * alv.x + h1f * alv.y + h2f * alv.z + h3f * alv.w;
    float pr = h0 * arv.x + h1f * arv.y + h2f * arv.z + h3f * arv.w;
#pragma unroll
    for (int mm = 1; mm < 8; mm <<= 1) {
        pl += __shfl_xor(pl, mm);
        pr += __shfl_xor(pr, mm);
    }
    if ((m & 7) == 0) {
        alc[i * 4 + g] = pl;
        arc[i * 4 + g] = pr;
    }
}

// ---------------------------------------------------------------- edge aggregation

__device__ __forceinline__ float sigmoidf_fast(float x) {
    return 1.f / (1.f + __expf(-x));
}

__device__ __forceinline__ float dot8_f16(f16x8 a, f16x8 b) {
    float part = 0.f;
#if __has_builtin(__builtin_amdgcn_fdot2)
    f16x2* pa = (f16x2*)&a;
    f16x2* pb = (f16x2*)&b;
#pragma unroll
    for (int kk = 0; kk < 4; ++kk)
        part = __builtin_amdgcn_fdot2(pa[kk], pb[kk], part, false);
#else
#pragma unroll
    for (int kk = 0; kk < 8; ++kk) part += (float)a[kk] * (float)b[kk];
#endif
    return part;
}

// layer 1: wave per dst node, quarter-wave (16 lanes x f16x8) per edge.
__global__ void __launch_bounds__(256) edge1_k(const _Float16* __restrict__ h1,
                                               const float* __restrict__ al,
                                               const float* __restrict__ ar,
                                               const int* __restrict__ offsets,
                                               const int* __restrict__ srcs,
                                               const float* __restrict__ b1,
                                               _Float16* __restrict__ h2o) {
    int i = (blockIdx.x * blockDim.x + threadIdx.x) >> 6;
    int l = threadIdx.x & 63;
    if (i >= N_NODES) return;
    int q = l & 15;
    int head = q >> 3;
    int sub = l >> 4;

    f16x8 hi8 = ((const f16x8*)(h1 + (size_t)i * 128))[q];
    float ari = ar[i * 2 + head];
    int start = offsets[i], end = offsets[i + 1];
    float s = 0.f;
    float o0 = 0.f, o1 = 0.f, o2 = 0.f, o3 = 0.f, o4 = 0.f, o5 = 0.f, o6 = 0.f, o7 = 0.f;

    int p0 = start + sub, p1 = p0 + 4, p2 = p0 + 8;
    bool v0 = p0 < end, v1 = p1 < end, v2 = p2 < end;
    int j0 = srcs[v0 ? p0 : start];
    int j1 = srcs[v1 ? p1 : start];
    int j2 = srcs[v2 ? p2 : start];
    f16x8 q0 = ((const f16x8*)(h1 + (size_t)j0 * 128))[q];
    f16x8 q1 = ((const f16x8*)(h1 + (size_t)j1 * 128))[q];
    f16x8 q2 = ((const f16x8*)(h1 + (size_t)j2 * 128))[q];
    float a0 = al[j0 * 2 + head];
    float a1 = al[j1 * 2 + head];
    float a2 = al[j2 * 2 + head];

    for (int pb = start; pb < end; pb += 4) {
        f16x8 hc = q0; float ac = a0; bool vc = v0;
        q0 = q1; a0 = a1; v0 = v1;
        q1 = q2; a1 = a2; v1 = v2;
        p2 += 4;
        v2 = p2 < end;
        int jn = srcs[v2 ? p2 : start];
        q2 = ((const f16x8*)(h1 + (size_t)jn * 128))[q];
        a2 = al[jn * 2 + head];

        float part = dot8_f16(hi8, hc);
        part += __shfl_xor(part, 1);
        part += __shfl_xor(part, 2);
        part += __shfl_xor(part, 4);
        float a = (ac + ari) * sigmoidf_fast(part);
        a = (a > 0.f) ? a : 0.2f * a;
        a = fminf(a, 60.f);
        float w = vc ? __expf(a) : 0.f;
        s += w;
        o0 += w * (float)hc[0]; o1 += w * (float)hc[1];
        o2 += w * (float)hc[2]; o3 += w * (float)hc[3];
        o4 += w * (float)hc[4]; o5 += w * (float)hc[5];
        o6 += w * (float)hc[6]; o7 += w * (float)hc[7];
    }
    s  += __shfl_xor(s, 16);  s  += __shfl_xor(s, 32);
    o0 += __shfl_xor(o0, 16); o0 += __shfl_xor(o0, 32);
    o1 += __shfl_xor(o1, 16); o1 += __shfl_xor(o1, 32);
    o2 += __shfl_xor(o2, 16); o2 += __shfl_xor(o2, 32);
    o3 += __shfl_xor(o3, 16); o3 += __shfl_xor(o3, 32);
    o4 += __shfl_xor(o4, 16); o4 += __shfl_xor(o4, 32);
    o5 += __shfl_xor(o5, 16); o5 += __shfl_xor(o5, 32);
    o6 += __shfl_xor(o6, 16); o6 += __shfl_xor(o6, 32);
    o7 += __shfl_xor(o7, 16); o7 += __shfl_xor(o7, 32);
    if (l < 16) {
        float inv = 1.f / (s + 1e-16f);
        float4 bva = ((const float4*)b1)[l * 2];
        float4 bvb = ((const float4*)b1)[l * 2 + 1];
        float r0 = o0 * inv + bva.x, r1 = o1 * inv + bva.y;
        float r2 = o2 * inv + bva.z, r3 = o3 * inv + bva.w;
        float r4 = o4 * inv + bvb.x, r5 = o5 * inv + bvb.y;
        float r6 = o6 * inv + bvb.z, r7 = o7 * inv + bvb.w;
        r0 = (r0 > 0.f) ? r0 : (__expf(r0) - 1.f);
        r1 = (r1 > 0.f) ? r1 : (__expf(r1) - 1.f);
        r2 = (r2 > 0.f) ? r2 : (__expf(r2) - 1.f);
        r3 = (r3 > 0.f) ? r3 : (__expf(r3) - 1.f);
        r4 = (r4 > 0.f) ? r4 : (__expf(r4) - 1.f);
        r5 = (r5 > 0.f) ? r5 : (__expf(r5) - 1.f);
        r6 = (r6 > 0.f) ? r6 : (__expf(r6) - 1.f);
        r7 = (r7 > 0.f) ? r7 : (__expf(r7) - 1.f);
        f16x8 r;
        r[0] = (_Float16)r0; r[1] = (_Float16)r1; r[2] = (_Float16)r2; r[3] = (_Float16)r3;
        r[4] = (_Float16)r4; r[5] = (_Float16)r5; r[6] = (_Float16)r6; r[7] = (_Float16)r7;
        ((f16x8*)(h2o + (size_t)i * 128))[l] = r;
    }
}

// layers 2+3 fused: wave per dst node, quarter-wave per edge; 4-lane groups
// over hcat row = [mu h0 | mu h1 | ls h0 | ls h1]. Writes d_out (fp32).
__global__ void __launch_bounds__(256) edge23_k(const _Float16* __restrict__ hcat,
                                                const float* __restrict__ alc,
                                                const float* __restrict__ arc,
                                                const int* __restrict__ offsets,
                                                const int* __restrict__ srcs,
                                                const float* __restrict__ bmu,
                                                const float* __restrict__ bls,
                                                float* __restrict__ out) {
    int i = (blockIdx.x * blockDim.x + threadIdx.x) >> 6;
    int l = threadIdx.x & 63;
    if (i >= N_NODES) return;
    int q = l & 15;
    int g = (l >> 2) & 3;
    int sub = l >> 4;

    f16x8 hi8 = ((const f16x8*)(hcat + (size_t)i * 128))[q];
    float ari = arc[i * 4 + g];
    int start = offsets[i], end = offsets[i + 1];
    float s = 0.f;
    float o0 = 0.f, o1 = 0.f, o2 = 0.f, o3 = 0.f, o4 = 0.f, o5 = 0.f, o6 = 0.f, o7 = 0.f;

    int p0 = start + sub, p1 = p0 + 4, p2 = p0 + 8;
    bool v0 = p0 < end, v1 = p1 < end, v2 = p2 < end;
    int j0 = srcs[v0 ? p0 : start];
    int j1 = srcs[v1 ? p1 : start];
    int j2 = srcs[v2 ? p2 : start];
    f16x8 q0 = ((const f16x8*)(hcat + (size_t)j0 * 128))[q];
    f16x8 q1 = ((const f16x8*)(hcat + (size_t)j1 * 128))[q];
    f16x8 q2 = ((const f16x8*)(hcat + (size_t)j2 * 128))[q];
    float a0 = alc[j0 * 4 + g];
    float a1 = alc[j1 * 4 + g];
    float a2 = alc[j2 * 4 + g];

    for (int pb = start; pb < end; pb += 4) {
        f16x8 hc = q0; float ac = a0; bool vc = v0;
        q0 = q1; a0 = a1; v0 = v1;
        q1 = q2; a1 = a2; v1 = v2;
        p2 += 4;
        v2 = p2 < end;
        int jn = srcs[v2 ? p2 : start];
        q2 = ((const f16x8*)(hcat + (size_t)jn * 128))[q];
        a2 = alc[jn * 4 + g];

        float part = dot8_f16(hi8, hc);
        part += __shfl_xor(part, 1);
        part += __shfl_xor(part, 2);
        float a = (ac + ari) * sigmoidf_fast(part);
        a = (a > 0.f) ? a : 0.2f * a;
        a = fminf(a, 60.f);
        float w = vc ? __expf(a) : 0.f;
        s += w;
        o0 += w * (float)hc[0]; o1 += w * (float)hc[1];
        o2 += w * (float)hc[2]; o3 += w * (float)hc[3];
        o4 += w * (float)hc[4]; o5 += w * (float)hc[5];
        o6 += w * (float)hc[6]; o7 += w * (float)hc[7];
    }
    s  += __shfl_xor(s, 16);  s  += __shfl_xor(s, 32);
    o0 += __shfl_xor(o0, 16); o0 += __shfl_xor(o0, 32);
    o1 += __shfl_xor(o1, 16); o1 += __shfl_xor(o1, 32);
    o2 += __shfl_xor(o2, 16); o2 += __shfl_xor(o2, 32);
    o3 += __shfl_xor(o3, 16); o3 += __shfl_xor(o3, 32);
    o4 += __shfl_xor(o4, 16); o4 += __shfl_xor(o4, 32);
    o5 += __shfl_xor(o5, 16); o5 += __shfl_xor(o5, 32);
    o6 += __shfl_xor(o6, 16); o6 += __shfl_xor(o6, 32);
    o7 += __shfl_xor(o7, 16); o7 += __shfl_xor(o7, 32);
    if (l < 16) {
        float inv = 1.f / (s + 1e-16f);
        int br = l >> 3;
        int c0 = 8 * (l & 7);
        const float* b = br ? bls : bmu;
        float4 bva = ((const float4*)(b + c0))[0];
        float4 bvb = ((const float4*)(b + c0))[1];
        float4 ra, rb;
        ra.x = o0 * inv + bva.x; ra.y = o1 * inv + bva.y;
        ra.z = o2 * inv + bva.z; ra.w = o3 * inv + bva.w;
        rb.x = o4 * inv + bvb.x; rb.y = o5 * inv + bvb.y;
        rb.z = o6 * inv + bvb.z; rb.w = o7 * inv + bvb.w;
        float* dst = out + (size_t)br * (N_NODES * 64) + (size_t)i * 64 + c0;
        ((float4*)dst)[0] = ra;
        ((float4*)dst)[1] = rb;
    }
}

// ---------------------------------------------------------------- launcher

extern "C" void kernel_launch(void* const* d_in, const int* in_sizes, int n_in,
                              void* d_out, int out_size, void* d_ws, size_t ws_size,
                              hipStream_t stream) {
    const float* x      = (const float*)d_in[0];
    const int*   ei     = (const int*)d_in[1];
    const float* W1     = (const float*)d_in[2];
    const float* att_l1 = (const float*)d_in[3];
    const float* att_r1 = (const float*)d_in[4];
    const float* b1     = (const float*)d_in[5];
    const float* Wmu    = (const float*)d_in[6];
    const float* attlmu = (const float*)d_in[7];
    const float* attrmu = (const float*)d_in[8];
    const float* bmu    = (const float*)d_in[9];
    const float* Wls    = (const float*)d_in[10];
    const float* attlls = (const float*)d_in[11];
    const float* attrls = (const float*)d_in[12];
    const float* bls    = (const float*)d_in[13];
    float* out = (float*)d_out;

    _Float16* h1   = (_Float16*)d_ws;         // 6,400,000 halfs
    _Float16* h2   = h1 + 6400000;            // 6,400,000 halfs
    _Float16* hcat = h2 + 6400000;            // 6,400,000 halfs
    float* al1   = (float*)(hcat + 6400000);  // 100,000
    float* ar1   = al1 + 100000;              // 100,000
    float* alc   = ar1 + 100000;              // 200,000
    float* arc   = alc + 200000;              // 200,000
    int* counts  = (int*)(arc + 200000);      // 50,000
    int* fill    = counts + 50000;            // 50,000
    int* offsets = fill + 50000;              // 50,016
    int* srcs    = offsets + 50016;           // 850,000
    int* bsums   = srcs + 850000;             // 256
    int* bbase   = bsums + 256;               // 256

    hipMemsetAsync(counts, 0, 50000 * sizeof(int), stream);
    hipMemsetAsync(fill, 0, 50000 * sizeof(int), stream);

    int ethreads = 256;
    int eblocks = (ETOT + ethreads - 1) / ethreads;
    hist_k<<<eblocks, ethreads, 0, stream>>>(ei, counts);
    reduce_k<<<SCAN_BLOCKS, 256, 0, stream>>>(counts, bsums);
    scansums_k<<<1, 256, 0, stream>>>(bsums, bbase);
    scanblk_k<<<SCAN_BLOCKS, 256, 0, stream>>>(counts, bbase, offsets);
    scatter_k<<<eblocks, ethreads, 0, stream>>>(ei, offsets, fill, srcs);

    gemm_mfma_f32A_k<<<GEMM_TILES, 256, 0, stream>>>(x, W1, nullptr, h1, N_NODES);

    int nblocks = (N_NODES + 3) / 4;       // edge kernels: 4 waves (nodes) / block
    int ablocks = (N_NODES + 7) / 8;       // attn kernels: 2 nodes / wave
    attn1_k<<<ablocks, 256, 0, stream>>>(h1, att_l1, att_r1, al1, ar1);
    edge1_k<<<nblocks, 256, 0, stream>>>(h1, al1, ar1, offsets, srcs, b1, h2);

    gemm_mfma_f16A_k<<<GEMM_TILES, 256, 0, stream>>>(h2, Wmu, Wls, hcat, N_NODES);
    attn23_k<<<ablocks, 256, 0, stream>>>(hcat, attlmu, attrmu, attlls, attrls, alc, arc);
    edge23_k<<<nblocks, 256, 0, stream>>>(hcat, alc, arc, offsets, srcs, bmu, bls, out);
}

// Round 6
// 329.403 us; speedup vs baseline: 1.8505x; 1.0086x over previous
//
#include <hip/hip_runtime.h>
#include <math.h>

#define N_NODES 50000
#define N_EDGES 800000
#define ETOT    (N_EDGES + N_NODES)
#define SCAN_BLOCKS ((N_NODES + 255) / 256)   // 196
#define GEMM_TILES ((N_NODES + 63) / 64)      // 782
#define NPART 8
#define PART_SIZE (N_NODES / NPART)           // 6250
#define CHUNK_EDGES 2048
#define NCHUNK ((ETOT + CHUNK_EDGES - 1) / CHUNK_EDGES)  // 416

typedef _Float16 f16x8 __attribute__((ext_vector_type(8)));   // 16 B
typedef _Float16 f16x4 __attribute__((ext_vector_type(4)));   // 8 B
typedef _Float16 f16x2 __attribute__((ext_vector_type(2)));   // 4 B
typedef float    f32x4 __attribute__((ext_vector_type(4)));

// ---------------------------------------------------------------- CSR build
// Both hist and scatter are dst-range partitioned: partition = blockIdx & 7
// so (with round-robin block->XCD dispatch) all RMW/stores to a given
// counts/srcs cache line come from one XCD -> no cross-XCD writeback storm.

__global__ void __launch_bounds__(256) hist_k(const int* __restrict__ ei,
                                              int* __restrict__ counts) {
    int part = blockIdx.x & (NPART - 1);
    int chunk = blockIdx.x >> 3;
    int lo = part * PART_SIZE, hi = lo + PART_SIZE;
    int base = chunk * CHUNK_EDGES + threadIdx.x;
#pragma unroll
    for (int it = 0; it < CHUNK_EDGES / 256; ++it) {
        int e = base + it * 256;
        if (e >= ETOT) break;
        int d = (e < N_EDGES) ? ei[N_EDGES + e] : (e - N_EDGES);
        if (d >= lo && d < hi) atomicAdd(&counts[d], 1);
    }
}

__global__ void __launch_bounds__(256) reduce_k(const int* __restrict__ counts,
                                                int* __restrict__ blockSums) {
    __shared__ int red[256];
    int t = threadIdx.x;
    int i = blockIdx.x * 256 + t;
    red[t] = (i < N_NODES) ? counts[i] : 0;
    __syncthreads();
#pragma unroll
    for (int off = 128; off > 0; off >>= 1) {
        if (t < off) red[t] += red[t + off];
        __syncthreads();
    }
    if (t == 0) blockSums[blockIdx.x] = red[0];
}

__global__ void __launch_bounds__(256) scansums_k(int* __restrict__ blockSums,
                                                  int* __restrict__ blockBase) {
    __shared__ int s[256];
    int t = threadIdx.x;
    int v = (t < SCAN_BLOCKS) ? blockSums[t] : 0;
    s[t] = v;
    __syncthreads();
#pragma unroll
    for (int off = 1; off < 256; off <<= 1) {
        int u = (t >= off) ? s[t - off] : 0;
        __syncthreads();
        s[t] += u;
        __syncthreads();
    }
    if (t < SCAN_BLOCKS) blockBase[t] = s[t] - v;
}

__global__ void __launch_bounds__(256) scanblk_k(const int* __restrict__ counts,
                                                 const int* __restrict__ blockBase,
                                                 int* __restrict__ offsets) {
    __shared__ int s[256];
    int t = threadIdx.x;
    int i = blockIdx.x * 256 + t;
    int v = (i < N_NODES) ? counts[i] : 0;
    s[t] = v;
    __syncthreads();
#pragma unroll
    for (int off = 1; off < 256; off <<= 1) {
        int u = (t >= off) ? s[t - off] : 0;
        __syncthreads();
        s[t] += u;
        __syncthreads();
    }
    int base = blockBase[blockIdx.x];
    int incl = base + s[t];
    if (i < N_NODES) offsets[i] = incl - v;
    if (i == N_NODES - 1) offsets[N_NODES] = incl;
}

__global__ void __launch_bounds__(256) scatter_k(const int* __restrict__ ei,
                                                 const int* __restrict__ offsets,
                                                 int* __restrict__ fill,
                                                 unsigned short* __restrict__ srcs) {
    int part = blockIdx.x & (NPART - 1);
    int chunk = blockIdx.x >> 3;
    int lo = part * PART_SIZE, hi = lo + PART_SIZE;
    int base = chunk * CHUNK_EDGES + threadIdx.x;
#pragma unroll
    for (int it = 0; it < CHUNK_EDGES / 256; ++it) {
        int e = base + it * 256;
        if (e >= ETOT) break;
        int d = (e < N_EDGES) ? ei[N_EDGES + e] : (e - N_EDGES);
        if (d >= lo && d < hi) {
            int s = (e < N_EDGES) ? ei[e] : d;
            int pos = offsets[d] + atomicAdd(&fill[d], 1);
            srcs[pos] = (unsigned short)s;
        }
    }
}

// ---------------------------------------------------------------- MFMA GEMMs (M x 128 @ 128 x 128)

__device__ __forceinline__ void stage_B(const float* __restrict__ B0,
                                        const float* __restrict__ B1,
                                        _Float16* Braw, _Float16* Bt, int t) {
    if (B1 == nullptr) {
        for (int it = 0; it < 16; ++it) {
            int id = it * 256 + t;
            int k = id >> 5, c4 = id & 31;
            float4 v = ((const float4*)B0)[id];
            _Float16* d = &Braw[k * 128 + c4 * 4];
            d[0] = (_Float16)v.x; d[1] = (_Float16)v.y;
            d[2] = (_Float16)v.z; d[3] = (_Float16)v.w;
        }
    } else {
        for (int it = 0; it < 8; ++it) {
            int id = it * 256 + t;
            int k = id >> 4, c4 = id & 15;
            float4 v = ((const float4*)B0)[id];
            _Float16* d = &Braw[k * 128 + c4 * 4];
            d[0] = (_Float16)v.x; d[1] = (_Float16)v.y;
            d[2] = (_Float16)v.z; d[3] = (_Float16)v.w;
            float4 w = ((const float4*)B1)[id];
            _Float16* e = &Braw[k * 128 + 64 + c4 * 4];
            e[0] = (_Float16)w.x; e[1] = (_Float16)w.y;
            e[2] = (_Float16)w.z; e[3] = (_Float16)w.w;
        }
    }
    __syncthreads();
    for (int it = 0; it < 8; ++it) {
        int id = it * 256 + t;
        int n = id >> 4, gk = id & 15;
        f16x8 g;
#pragma unroll
        for (int j = 0; j < 8; ++j) g[j] = Braw[(gk * 8 + j) * 128 + n];
        int gs = gk ^ (n & 7);
        *(f16x8*)&Bt[n * 128 + gs * 8] = g;
    }
    __syncthreads();
}

__device__ __forceinline__ void gemm_core(const f16x8 a[4], const _Float16* Bt,
                                          _Float16* cs, _Float16* __restrict__ C,
                                          int r0, int l) {
    int i16 = l & 15, q = l >> 4;
    f32x4 acc[8];
#pragma unroll
    for (int tt = 0; tt < 8; ++tt) acc[tt] = (f32x4){0.f, 0.f, 0.f, 0.f};
#pragma unroll
    for (int kb = 0; kb < 4; ++kb) {
#pragma unroll
        for (int tt = 0; tt < 8; ++tt) {
            int n = tt * 16 + i16;
            int gs = (kb * 4 + q) ^ (n & 7);
            f16x8 b = *(const f16x8*)&Bt[n * 128 + gs * 8];
            acc[tt] = __builtin_amdgcn_mfma_f32_16x16x32_f16(a[kb], b, acc[tt], 0, 0, 0);
        }
    }
#pragma unroll
    for (int tt = 0; tt < 8; ++tt)
#pragma unroll
        for (int r = 0; r < 4; ++r)
            cs[(q * 4 + r) * 128 + tt * 16 + i16] = (_Float16)acc[tt][r];
#pragma unroll
    for (int u = 0; u < 4; ++u) {
        int idx = u * 64 + l;
        int rr = idx >> 4, cc = idx & 15;
        ((f16x8*)(C + (size_t)(r0 + rr) * 128))[cc] = ((f16x8*)cs)[idx];
    }
}

__global__ void __launch_bounds__(256) gemm_mfma_f32A_k(const float* __restrict__ A,
                                                        const float* __restrict__ B0,
                                                        const float* __restrict__ B1,
                                                        _Float16* __restrict__ C, int M) {
    __shared__ _Float16 Braw[128 * 128];
    __shared__ _Float16 Bt[128 * 128];
    __shared__ _Float16 Cst[4][16 * 128];
    int t = threadIdx.x;
    stage_B(B0, B1, Braw, Bt, t);
    int wave = t >> 6, l = t & 63;
    int i16 = l & 15, q = l >> 4;
    for (int tile = blockIdx.x; tile * 64 < M; tile += gridDim.x) {
        int r0 = tile * 64 + wave * 16;
        if (r0 >= M) continue;
        const float* ar_ = A + (size_t)(r0 + i16) * 128;
        f16x8 a[4];
#pragma unroll
        for (int kb = 0; kb < 4; ++kb) {
            float4 u = ((const float4*)(ar_ + kb * 32 + q * 8))[0];
            float4 v = ((const float4*)(ar_ + kb * 32 + q * 8))[1];
            f16x8 t8;
            t8[0] = (_Float16)u.x; t8[1] = (_Float16)u.y;
            t8[2] = (_Float16)u.z; t8[3] = (_Float16)u.w;
            t8[4] = (_Float16)v.x; t8[5] = (_Float16)v.y;
            t8[6] = (_Float16)v.z; t8[7] = (_Float16)v.w;
            a[kb] = t8;
        }
        gemm_core(a, Bt, &Cst[wave][0], C, r0, l);
    }
}

__global__ void __launch_bounds__(256) gemm_mfma_f16A_k(const _Float16* __restrict__ A,
                                                        const float* __restrict__ B0,
                                                        const float* __restrict__ B1,
                                                        _Float16* __restrict__ C, int M) {
    __shared__ _Float16 Braw[128 * 128];
    __shared__ _Float16 Bt[128 * 128];
    __shared__ _Float16 Cst[4][16 * 128];
    int t = threadIdx.x;
    stage_B(B0, B1, Braw, Bt, t);
    int wave = t >> 6, l = t & 63;
    int i16 = l & 15, q = l >> 4;
    for (int tile = blockIdx.x; tile * 64 < M; tile += gridDim.x) {
        int r0 = tile * 64 + wave * 16;
        if (r0 >= M) continue;
        const _Float16* ar_ = A + (size_t)(r0 + i16) * 128;
        f16x8 a[4];
#pragma unroll
        for (int kb = 0; kb < 4; ++kb)
            a[kb] = *(const f16x8*)(ar_ + kb * 32 + q * 8);
        gemm_core(a, Bt, &Cst[wave][0], C, r0, l);
    }
}

// ---------------------------------------------------------------- attention coefficients

__global__ void attn1_k(const _Float16* __restrict__ h, const float* __restrict__ attl,
                        const float* __restrict__ attr, float* __restrict__ al,
                        float* __restrict__ ar) {
    int wid = (blockIdx.x * blockDim.x + threadIdx.x) >> 6;
    int l = threadIdx.x & 63;
    int i = wid * 2 + (l >> 5);
    if (i >= N_NODES) return;
    int m = l & 31;
    int head = m >> 4;
    f16x4 hv = ((const f16x4*)(h + (size_t)i * 128))[m];
    float4 alv = ((const float4*)(attl + head * 64))[m & 15];
    float4 arv = ((const float4*)(attr + head * 64))[m & 15];
    float h0 = (float)hv[0], h1f = (float)hv[1], h2f = (float)hv[2], h3f = (float)hv[3];
    float pl = h0 * alv.x + h1f * alv.y + h2f * alv.z + h3f * alv.w;
    float pr = h0 * arv.x + h1f * arv.y + h2f * arv.z + h3f * arv.w;
#pragma unroll
    for (int mm = 1; mm < 16; mm <<= 1) {
        pl += __shfl_xor(pl, mm);
        pr += __shfl_xor(pr, mm);
    }
    if ((m & 15) == 0) {
        al[i * 2 + head] = pl;
        ar[i * 2 + head] = pr;
    }
}

__global__ void attn23_k(const _Float16* __restrict__ hcat,
                         const float* __restrict__ attlmu, const float* __restrict__ attrmu,
                         const float* __restrict__ attlls, const float* __restrict__ attrls,
                         float* __restrict__ alc, float* __restrict__ arc) {
    int wid = (blockIdx.x * blockDim.x + threadIdx.x) >> 6;
    int l = threadIdx.x & 63;
    int i = wid * 2 + (l >> 5);
    if (i >= N_NODES) return;
    int m = l & 31;
    int g = m >> 3;
    int head = g & 1;
    int br = g >> 1;
    f16x4 hv = ((const f16x4*)(hcat + (size_t)i * 128))[m];
    const float* attl = br ? attlls : attlmu;
    const float* attr = br ? attrls : attrmu;
    float4 alv = ((const float4*)(attl + head * 32))[m & 7];
    float4 arv = ((const float4*)(attr + head * 32))[m & 7];
    float h0 = (float)hv[0], h1f = (float)hv[1], h2f = (float)hv[2], h3f = (float)hv[3];
    float pl = h0 * alv.x + h1f * alv.y + h2f * alv.z + h3f * alv.w;
    float pr = h0 * arv.x + h1f * arv.y + h2f * arv.z + h3f * arv.w;
#pragma unroll
    for (int mm = 1; mm < 8; mm <<= 1) {
        pl += __shfl_xor(pl, mm);
        pr += __shfl_xor(pr, mm);
    }
    if ((m & 7) == 0) {
        alc[i * 4 + g] = pl;
        arc[i * 4 + g] = pr;
    }
}

// ---------------------------------------------------------------- edge aggregation

__device__ __forceinline__ float sigmoidf_fast(float x) {
    return 1.f / (1.f + __expf(-x));
}

__device__ __forceinline__ float dot8_f16(f16x8 a, f16x8 b) {
    float part = 0.f;
#if __has_builtin(__builtin_amdgcn_fdot2)
    f16x2* pa = (f16x2*)&a;
    f16x2* pb = (f16x2*)&b;
#pragma unroll
    for (int kk = 0; kk < 4; ++kk)
        part = __builtin_amdgcn_fdot2(pa[kk], pb[kk], part, false);
#else
#pragma unroll
    for (int kk = 0; kk < 8; ++kk) part += (float)a[kk] * (float)b[kk];
#endif
    return part;
}

// layer 1: wave per dst node, quarter-wave (16 lanes x f16x8) per edge.
__global__ void __launch_bounds__(256) edge1_k(const _Float16* __restrict__ h1,
                                               const float* __restrict__ al,
                                               const float* __restrict__ ar,
                                               const int* __restrict__ offsets,
                                               const unsigned short* __restrict__ srcs,
                                               const float* __restrict__ b1,
                                               _Float16* __restrict__ h2o) {
    int i = (blockIdx.x * blockDim.x + threadIdx.x) >> 6;
    int l = threadIdx.x & 63;
    if (i >= N_NODES) return;
    int q = l & 15;
    int head = q >> 3;
    int sub = l >> 4;

    f16x8 hi8 = ((const f16x8*)(h1 + (size_t)i * 128))[q];
    float ari = ar[i * 2 + head];
    int start = offsets[i], end = offsets[i + 1];
    float s = 0.f;
    float o0 = 0.f, o1 = 0.f, o2 = 0.f, o3 = 0.f, o4 = 0.f, o5 = 0.f, o6 = 0.f, o7 = 0.f;

    int p0 = start + sub, p1 = p0 + 4, p2 = p0 + 8;
    bool v0 = p0 < end, v1 = p1 < end, v2 = p2 < end;
    int j0 = srcs[v0 ? p0 : start];
    int j1 = srcs[v1 ? p1 : start];
    int j2 = srcs[v2 ? p2 : start];
    f16x8 q0 = ((const f16x8*)(h1 + (size_t)j0 * 128))[q];
    f16x8 q1 = ((const f16x8*)(h1 + (size_t)j1 * 128))[q];
    f16x8 q2 = ((const f16x8*)(h1 + (size_t)j2 * 128))[q];
    float a0 = al[j0 * 2 + head];
    float a1 = al[j1 * 2 + head];
    float a2 = al[j2 * 2 + head];

    for (int pb = start; pb < end; pb += 4) {
        f16x8 hc = q0; float ac = a0; bool vc = v0;
        q0 = q1; a0 = a1; v0 = v1;
        q1 = q2; a1 = a2; v1 = v2;
        p2 += 4;
        v2 = p2 < end;
        int jn = srcs[v2 ? p2 : start];
        q2 = ((const f16x8*)(h1 + (size_t)jn * 128))[q];
        a2 = al[jn * 2 + head];

        float part = dot8_f16(hi8, hc);
        part += __shfl_xor(part, 1);
        part += __shfl_xor(part, 2);
        part += __shfl_xor(part, 4);
        float a = (ac + ari) * sigmoidf_fast(part);
        a = (a > 0.f) ? a : 0.2f * a;
        a = fminf(a, 60.f);
        float w = vc ? __expf(a) : 0.f;
        s += w;
        o0 += w * (float)hc[0]; o1 += w * (float)hc[1];
        o2 += w * (float)hc[2]; o3 += w * (float)hc[3];
        o4 += w * (float)hc[4]; o5 += w * (float)hc[5];
        o6 += w * (float)hc[6]; o7 += w * (float)hc[7];
    }
    s  += __shfl_xor(s, 16);  s  += __shfl_xor(s, 32);
    o0 += __shfl_xor(o0, 16); o0 += __shfl_xor(o0, 32);
    o1 += __shfl_xor(o1, 16); o1 += __shfl_xor(o1, 32);
    o2 += __shfl_xor(o2, 16); o2 += __shfl_xor(o2, 32);
    o3 += __shfl_xor(o3, 16); o3 += __shfl_xor(o3, 32);
    o4 += __shfl_xor(o4, 16); o4 += __shfl_xor(o4, 32);
    o5 += __shfl_xor(o5, 16); o5 += __shfl_xor(o5, 32);
    o6 += __shfl_xor(o6, 16); o6 += __shfl_xor(o6, 32);
    o7 += __shfl_xor(o7, 16); o7 += __shfl_xor(o7, 32);
    if (l < 16) {
        float inv = 1.f / (s + 1e-16f);
        float4 bva = ((const float4*)b1)[l * 2];
        float4 bvb = ((const float4*)b1)[l * 2 + 1];
        float r0 = o0 * inv + bva.x, r1 = o1 * inv + bva.y;
        float r2 = o2 * inv + bva.z, r3 = o3 * inv + bva.w;
        float r4 = o4 * inv + bvb.x, r5 = o5 * inv + bvb.y;
        float r6 = o6 * inv + bvb.z, r7 = o7 * inv + bvb.w;
        r0 = (r0 > 0.f) ? r0 : (__expf(r0) - 1.f);
        r1 = (r1 > 0.f) ? r1 : (__expf(r1) - 1.f);
        r2 = (r2 > 0.f) ? r2 : (__expf(r2) - 1.f);
        r3 = (r3 > 0.f) ? r3 : (__expf(r3) - 1.f);
        r4 = (r4 > 0.f) ? r4 : (__expf(r4) - 1.f);
        r5 = (r5 > 0.f) ? r5 : (__expf(r5) - 1.f);
        r6 = (r6 > 0.f) ? r6 : (__expf(r6) - 1.f);
        r7 = (r7 > 0.f) ? r7 : (__expf(r7) - 1.f);
        f16x8 r;
        r[0] = (_Float16)r0; r[1] = (_Float16)r1; r[2] = (_Float16)r2; r[3] = (_Float16)r3;
        r[4] = (_Float16)r4; r[5] = (_Float16)r5; r[6] = (_Float16)r6; r[7] = (_Float16)r7;
        ((f16x8*)(h2o + (size_t)i * 128))[l] = r;
    }
}

// layers 2+3 fused: wave per dst node, quarter-wave per edge; writes d_out.
__global__ void __launch_bounds__(256) edge23_k(const _Float16* __restrict__ hcat,
                                                const float* __restrict__ alc,
                                                const float* __restrict__ arc,
                                                const int* __restrict__ offsets,
                                                const unsigned short* __restrict__ srcs,
                                                const float* __restrict__ bmu,
                                                const float* __restrict__ bls,
                                                float* __restrict__ out) {
    int i = (blockIdx.x * blockDim.x + threadIdx.x) >> 6;
    int l = threadIdx.x & 63;
    if (i >= N_NODES) return;
    int q = l & 15;
    int g = (l >> 2) & 3;
    int sub = l >> 4;

    f16x8 hi8 = ((const f16x8*)(hcat + (size_t)i * 128))[q];
    float ari = arc[i * 4 + g];
    int start = offsets[i], end = offsets[i + 1];
    float s = 0.f;
    float o0 = 0.f, o1 = 0.f, o2 = 0.f, o3 = 0.f, o4 = 0.f, o5 = 0.f, o6 = 0.f, o7 = 0.f;

    int p0 = start + sub, p1 = p0 + 4, p2 = p0 + 8;
    bool v0 = p0 < end, v1 = p1 < end, v2 = p2 < end;
    int j0 = srcs[v0 ? p0 : start];
    int j1 = srcs[v1 ? p1 : start];
    int j2 = srcs[v2 ? p2 : start];
    f16x8 q0 = ((const f16x8*)(hcat + (size_t)j0 * 128))[q];
    f16x8 q1 = ((const f16x8*)(hcat + (size_t)j1 * 128))[q];
    f16x8 q2 = ((const f16x8*)(hcat + (size_t)j2 * 128))[q];
    float a0 = alc[j0 * 4 + g];
    float a1 = alc[j1 * 4 + g];
    float a2 = alc[j2 * 4 + g];

    for (int pb = start; pb < end; pb += 4) {
        f16x8 hc = q0; float ac = a0; bool vc = v0;
        q0 = q1; a0 = a1; v0 = v1;
        q1 = q2; a1 = a2; v1 = v2;
        p2 += 4;
        v2 = p2 < end;
        int jn = srcs[v2 ? p2 : start];
        q2 = ((const f16x8*)(hcat + (size_t)jn * 128))[q];
        a2 = alc[jn * 4 + g];

        float part = dot8_f16(hi8, hc);
        part += __shfl_xor(part, 1);
        part += __shfl_xor(part, 2);
        float a = (ac + ari) * sigmoidf_fast(part);
        a = (a > 0.f) ? a : 0.2f * a;
        a = fminf(a, 60.f);
        float w = vc ? __expf(a) : 0.f;
        s += w;
        o0 += w * (float)hc[0]; o1 += w * (float)hc[1];
        o2 += w * (float)hc[2]; o3 += w * (float)hc[3];
        o4 += w * (float)hc[4]; o5 += w * (float)hc[5];
        o6 += w * (float)hc[6]; o7 += w * (float)hc[7];
    }
    s  += __shfl_xor(s, 16);  s  += __shfl_xor(s, 32);
    o0 += __shfl_xor(o0, 16); o0 += __shfl_xor(o0, 32);
    o1 += __shfl_xor(o1, 16); o1 += __shfl_xor(o1, 32);
    o2 += __shfl_xor(o2, 16); o2 += __shfl_xor(o2, 32);
    o3 += __shfl_xor(o3, 16); o3 += __shfl_xor(o3, 32);
    o4 += __shfl_xor(o4, 16); o4 += __shfl_xor(o4, 32);
    o5 += __shfl_xor(o5, 16); o5 += __shfl_xor(o5, 32);
    o6 += __shfl_xor(o6, 16); o6 += __shfl_xor(o6, 32);
    o7 += __shfl_xor(o7, 16); o7 += __shfl_xor(o7, 32);
    if (l < 16) {
        float inv = 1.f / (s + 1e-16f);
        int br = l >> 3;
        int c0 = 8 * (l & 7);
        const float* b = br ? bls : bmu;
        float4 bva = ((const float4*)(b + c0))[0];
        float4 bvb = ((const float4*)(b + c0))[1];
        float4 ra, rb;
        ra.x = o0 * inv + bva.x; ra.y = o1 * inv + bva.y;
        ra.z = o2 * inv + bva.z; ra.w = o3 * inv + bva.w;
        rb.x = o4 * inv + bvb.x; rb.y = o5 * inv + bvb.y;
        rb.z = o6 * inv + bvb.z; rb.w = o7 * inv + bvb.w;
        float* dst = out + (size_t)br * (N_NODES * 64) + (size_t)i * 64 + c0;
        ((float4*)dst)[0] = ra;
        ((float4*)dst)[1] = rb;
    }
}

// ---------------------------------------------------------------- launcher

extern "C" void kernel_launch(void* const* d_in, const int* in_sizes, int n_in,
                              void* d_out, int out_size, void* d_ws, size_t ws_size,
                              hipStream_t stream) {
    const float* x      = (const float*)d_in[0];
    const int*   ei     = (const int*)d_in[1];
    const float* W1     = (const float*)d_in[2];
    const float* att_l1 = (const float*)d_in[3];
    const float* att_r1 = (const float*)d_in[4];
    const float* b1     = (const float*)d_in[5];
    const float* Wmu    = (const float*)d_in[6];
    const float* attlmu = (const float*)d_in[7];
    const float* attrmu = (const float*)d_in[8];
    const float* bmu    = (const float*)d_in[9];
    const float* Wls    = (const float*)d_in[10];
    const float* attlls = (const float*)d_in[11];
    const float* attrls = (const float*)d_in[12];
    const float* bls    = (const float*)d_in[13];
    float* out = (float*)d_out;

    _Float16* h1   = (_Float16*)d_ws;         // 6,400,000 halfs
    _Float16* h2   = h1 + 6400000;            // 6,400,000 halfs
    _Float16* hcat = h2 + 6400000;            // 6,400,000 halfs
    float* al1   = (float*)(hcat + 6400000);  // 100,000
    float* ar1   = al1 + 100000;              // 100,000
    float* alc   = ar1 + 100000;              // 200,000
    float* arc   = alc + 200000;              // 200,000
    int* counts  = (int*)(arc + 200000);      // 50,000
    int* fill    = counts + 50000;            // 50,000
    int* offsets = fill + 50000;              // 50,016
    unsigned short* srcs = (unsigned short*)(offsets + 50016);  // 850,016 ushorts
    int* bsums   = (int*)(srcs + 850016);     // 256
    int* bbase   = bsums + 256;               // 256

    hipMemsetAsync(counts, 0, 50000 * sizeof(int), stream);
    hipMemsetAsync(fill, 0, 50000 * sizeof(int), stream);

    hist_k<<<NCHUNK * NPART, 256, 0, stream>>>(ei, counts);
    reduce_k<<<SCAN_BLOCKS, 256, 0, stream>>>(counts, bsums);
    scansums_k<<<1, 256, 0, stream>>>(bsums, bbase);
    scanblk_k<<<SCAN_BLOCKS, 256, 0, stream>>>(counts, bbase, offsets);
    scatter_k<<<NCHUNK * NPART, 256, 0, stream>>>(ei, offsets, fill, srcs);

    gemm_mfma_f32A_k<<<GEMM_TILES, 256, 0, stream>>>(x, W1, nullptr, h1, N_NODES);

    int nblocks = (N_NODES + 3) / 4;       // edge kernels: 4 waves (nodes) / block
    int ablocks = (N_NODES + 7) / 8;       // attn kernels: 2 nodes / wave
    attn1_k<<<ablocks, 256, 0, stream>>>(h1, att_l1, att_r1, al1, ar1);
    edge1_k<<<nblocks, 256, 0, stream>>>(h1, al1, ar1, offsets, srcs, b1, h2);

    gemm_mfma_f16A_k<<<GEMM_TILES, 256, 0, stream>>>(h2, Wmu, Wls, hcat, N_NODES);
    attn23_k<<<ablocks, 256, 0, stream>>>(hcat, attlmu, attrmu, attlls, attrls, alc, arc);
    edge23_k<<<nblocks, 256, 0, stream>>>(hcat, alc, arc, offsets, srcs, bmu, bls, out);
}

// Round 7
// 328.012 us; speedup vs baseline: 1.8583x; 1.0042x over previous
//
#include <hip/hip_runtime.h>
#include <math.h>

#define N_NODES 50000
#define N_EDGES 800000
#define ETOT    (N_EDGES + N_NODES)
#define SCAN_BLOCKS ((N_NODES + 255) / 256)   // 196
#define GEMM_TILES ((N_NODES + 63) / 64)      // 782 (covers 50048 rows)
#define NROWS 50048                            // padded h-table rows
#define SENT 50000                             // sentinel node (zero row, al=-1e30)
#define NPART 8
#define PART_SIZE (N_NODES / NPART)           // 6250
#define CHUNK_EDGES 2048
#define NCHUNK ((ETOT + CHUNK_EDGES - 1) / CHUNK_EDGES)  // 416

typedef _Float16 f16x8 __attribute__((ext_vector_type(8)));   // 16 B
typedef _Float16 f16x4 __attribute__((ext_vector_type(4)));   // 8 B
typedef _Float16 f16x2 __attribute__((ext_vector_type(2)));   // 4 B
typedef float    f32x4 __attribute__((ext_vector_type(4)));

// ---------------------------------------------------------------- CSR build (dst-range partitioned)

__global__ void __launch_bounds__(256) hist_k(const int* __restrict__ ei,
                                              int* __restrict__ counts) {
    int part = blockIdx.x & (NPART - 1);
    int chunk = blockIdx.x >> 3;
    int lo = part * PART_SIZE, hi = lo + PART_SIZE;
    int base = chunk * CHUNK_EDGES + threadIdx.x;
#pragma unroll
    for (int it = 0; it < CHUNK_EDGES / 256; ++it) {
        int e = base + it * 256;
        if (e >= ETOT) break;
        int d = (e < N_EDGES) ? ei[N_EDGES + e] : (e - N_EDGES);
        if (d >= lo && d < hi) atomicAdd(&counts[d], 1);
    }
}

// scans use PADDED counts: pc = (c+3) & ~3   (each segment multiple of 4)
__global__ void __launch_bounds__(256) reduce_k(const int* __restrict__ counts,
                                                int* __restrict__ blockSums) {
    __shared__ int red[256];
    int t = threadIdx.x;
    int i = blockIdx.x * 256 + t;
    red[t] = (i < N_NODES) ? ((counts[i] + 3) & ~3) : 0;
    __syncthreads();
#pragma unroll
    for (int off = 128; off > 0; off >>= 1) {
        if (t < off) red[t] += red[t + off];
        __syncthreads();
    }
    if (t == 0) blockSums[blockIdx.x] = red[0];
}

__global__ void __launch_bounds__(256) scansums_k(int* __restrict__ blockSums,
                                                  int* __restrict__ blockBase) {
    __shared__ int s[256];
    int t = threadIdx.x;
    int v = (t < SCAN_BLOCKS) ? blockSums[t] : 0;
    s[t] = v;
    __syncthreads();
#pragma unroll
    for (int off = 1; off < 256; off <<= 1) {
        int u = (t >= off) ? s[t - off] : 0;
        __syncthreads();
        s[t] += u;
        __syncthreads();
    }
    if (t < SCAN_BLOCKS) blockBase[t] = s[t] - v;
}

__global__ void __launch_bounds__(256) scanblk_k(const int* __restrict__ counts,
                                                 const int* __restrict__ blockBase,
                                                 int* __restrict__ offsets) {
    __shared__ int s[256];
    int t = threadIdx.x;
    int i = blockIdx.x * 256 + t;
    int v = (i < N_NODES) ? ((counts[i] + 3) & ~3) : 0;
    s[t] = v;
    __syncthreads();
#pragma unroll
    for (int off = 1; off < 256; off <<= 1) {
        int u = (t >= off) ? s[t - off] : 0;
        __syncthreads();
        s[t] += u;
        __syncthreads();
    }
    int base = blockBase[blockIdx.x];
    int incl = base + s[t];
    if (i < N_NODES) offsets[i] = incl - v;
    if (i == N_NODES - 1) offsets[N_NODES] = incl;
}

__global__ void __launch_bounds__(256) scatter_k(const int* __restrict__ ei,
                                                 const int* __restrict__ offsets,
                                                 int* __restrict__ fill,
                                                 unsigned short* __restrict__ srcs) {
    int part = blockIdx.x & (NPART - 1);
    int chunk = blockIdx.x >> 3;
    int lo = part * PART_SIZE, hi = lo + PART_SIZE;
    int base = chunk * CHUNK_EDGES + threadIdx.x;
#pragma unroll
    for (int it = 0; it < CHUNK_EDGES / 256; ++it) {
        int e = base + it * 256;
        if (e >= ETOT) break;
        int d = (e < N_EDGES) ? ei[N_EDGES + e] : (e - N_EDGES);
        if (d >= lo && d < hi) {
            int s = (e < N_EDGES) ? ei[e] : d;
            int pos = offsets[d] + atomicAdd(&fill[d], 1);
            srcs[pos] = (unsigned short)s;
        }
    }
}

// fill pad slots (and array tail) with the sentinel node
__global__ void __launch_bounds__(256) pad_k(const int* __restrict__ counts,
                                             const int* __restrict__ offsets,
                                             unsigned short* __restrict__ srcs) {
    int i = blockIdx.x * blockDim.x + threadIdx.x;
    if (i < N_NODES) {
        int c = counts[i];
        int e = offsets[i + 1];
        for (int p = offsets[i] + c; p < e; ++p) srcs[p] = (unsigned short)SENT;
    }
    if (i == 0) {
        int tot = offsets[N_NODES];
        for (int p = tot; p < tot + 64; ++p) srcs[p] = (unsigned short)SENT;
    }
}

// ---------------------------------------------------------------- MFMA GEMMs (fused attn epilogue)

__device__ __forceinline__ void stage_B(const float* __restrict__ B0,
                                        const float* __restrict__ B1,
                                        _Float16* Braw, _Float16* Bt, int t) {
    if (B1 == nullptr) {
        for (int it = 0; it < 16; ++it) {
            int id = it * 256 + t;
            int k = id >> 5, c4 = id & 31;
            float4 v = ((const float4*)B0)[id];
            _Float16* d = &Braw[k * 128 + c4 * 4];
            d[0] = (_Float16)v.x; d[1] = (_Float16)v.y;
            d[2] = (_Float16)v.z; d[3] = (_Float16)v.w;
        }
    } else {
        for (int it = 0; it < 8; ++it) {
            int id = it * 256 + t;
            int k = id >> 4, c4 = id & 15;
            float4 v = ((const float4*)B0)[id];
            _Float16* d = &Braw[k * 128 + c4 * 4];
            d[0] = (_Float16)v.x; d[1] = (_Float16)v.y;
            d[2] = (_Float16)v.z; d[3] = (_Float16)v.w;
            float4 w = ((const float4*)B1)[id];
            _Float16* e = &Braw[k * 128 + 64 + c4 * 4];
            e[0] = (_Float16)w.x; e[1] = (_Float16)w.y;
            e[2] = (_Float16)w.z; e[3] = (_Float16)w.w;
        }
    }
    __syncthreads();
    for (int it = 0; it < 8; ++it) {
        int id = it * 256 + t;
        int n = id >> 4, gk = id & 15;
        f16x8 g;
#pragma unroll
        for (int j = 0; j < 8; ++j) g[j] = Braw[(gk * 8 + j) * 128 + n];
        int gs = gk ^ (n & 7);
        *(f16x8*)&Bt[n * 128 + gs * 8] = g;
    }
    __syncthreads();
}

__device__ __forceinline__ void mfma_tile(const f16x8 a[4], const _Float16* Bt,
                                          f32x4 acc[8], int l) {
    int i16 = l & 15, q = l >> 4;
#pragma unroll
    for (int tt = 0; tt < 8; ++tt) acc[tt] = (f32x4){0.f, 0.f, 0.f, 0.f};
#pragma unroll
    for (int kb = 0; kb < 4; ++kb) {
#pragma unroll
        for (int tt = 0; tt < 8; ++tt) {
            int n = tt * 16 + i16;
            int gs = (kb * 4 + q) ^ (n & 7);
            f16x8 b = *(const f16x8*)&Bt[n * 128 + gs * 8];
            acc[tt] = __builtin_amdgcn_mfma_f32_16x16x32_f16(a[kb], b, acc[tt], 0, 0, 0);
        }
    }
}

__device__ __forceinline__ void store_C(const f32x4 acc[8], _Float16* cs,
                                        _Float16* __restrict__ C, int r0, int l) {
    int i16 = l & 15, q = l >> 4;
#pragma unroll
    for (int tt = 0; tt < 8; ++tt)
#pragma unroll
        for (int r = 0; r < 4; ++r)
            cs[(q * 4 + r) * 128 + tt * 16 + i16] = (_Float16)acc[tt][r];
#pragma unroll
    for (int u = 0; u < 4; ++u) {
        int idx = u * 64 + l;
        int rr = idx >> 4, cc = idx & 15;
        f16x8 v = ((f16x8*)cs)[idx];
        if (r0 + rr >= N_NODES) v = (f16x8)(_Float16)0.f;   // sentinel rows = 0
        ((f16x8*)(C + (size_t)(r0 + rr) * 128))[cc] = v;
    }
}

// gemm1: A fp32 [N,128], B = W1 [128x128]; fused attn1 epilogue -> al/ar [N,2]
__global__ void __launch_bounds__(256) gemm1_k(const float* __restrict__ A,
                                               const float* __restrict__ B0,
                                               const float* __restrict__ att_l,
                                               const float* __restrict__ att_r,
                                               _Float16* __restrict__ C,
                                               float* __restrict__ al,
                                               float* __restrict__ ar) {
    __shared__ _Float16 Braw[128 * 128];
    __shared__ _Float16 Bt[128 * 128];
    __shared__ _Float16 Cst[4][16 * 128];
    int t = threadIdx.x;
    stage_B(B0, nullptr, Braw, Bt, t);
    int wave = t >> 6, l = t & 63;
    int i16 = l & 15, q = l >> 4;
    float attL[8], attR[8];
#pragma unroll
    for (int tt = 0; tt < 8; ++tt) {
        int col = tt * 16 + i16;
        attL[tt] = att_l[col];
        attR[tt] = att_r[col];
    }
    int r0 = blockIdx.x * 64 + wave * 16;
    const float* ar_ = A + (size_t)min(r0 + i16, N_NODES - 1) * 128;
    f16x8 a[4];
#pragma unroll
    for (int kb = 0; kb < 4; ++kb) {
        float4 u = ((const float4*)(ar_ + kb * 32 + q * 8))[0];
        float4 v = ((const float4*)(ar_ + kb * 32 + q * 8))[1];
        f16x8 t8;
        t8[0] = (_Float16)u.x; t8[1] = (_Float16)u.y;
        t8[2] = (_Float16)u.z; t8[3] = (_Float16)u.w;
        t8[4] = (_Float16)v.x; t8[5] = (_Float16)v.y;
        t8[6] = (_Float16)v.z; t8[7] = (_Float16)v.w;
        a[kb] = t8;
    }
    f32x4 acc[8];
    mfma_tile(a, Bt, acc, l);
    store_C(acc, &Cst[wave][0], C, r0, l);
    // attn epilogue: pl/pr per (head, r), reduced over the 16-lane i16 group
    float pl[2][4], pr[2][4];
#pragma unroll
    for (int h = 0; h < 2; ++h)
#pragma unroll
        for (int r = 0; r < 4; ++r) {
            float sl = 0.f, sr = 0.f;
#pragma unroll
            for (int k = 0; k < 4; ++k) {
                float v = acc[h * 4 + k][r];
                sl += v * attL[h * 4 + k];
                sr += v * attR[h * 4 + k];
            }
            pl[h][r] = sl; pr[h][r] = sr;
        }
#pragma unroll
    for (int m = 1; m < 16; m <<= 1) {
#pragma unroll
        for (int h = 0; h < 2; ++h)
#pragma unroll
            for (int r = 0; r < 4; ++r) {
                pl[h][r] += __shfl_xor(pl[h][r], m);
                pr[h][r] += __shfl_xor(pr[h][r], m);
            }
    }
    if (i16 == 0) {
#pragma unroll
        for (int h = 0; h < 2; ++h)
#pragma unroll
            for (int r = 0; r < 4; ++r) {
                int row = r0 + q * 4 + r;
                bool sent = (row >= N_NODES);
                al[row * 2 + h] = sent ? -1e30f : pl[h][r];
                ar[row * 2 + h] = sent ? 0.f : pr[h][r];
            }
    }
}

// gemm2: A fp16 h2, B = [Wmu|Wls]; fused attn23 epilogue -> alc/arc [N,4]
__global__ void __launch_bounds__(256) gemm2_k(const _Float16* __restrict__ A,
                                               const float* __restrict__ B0,
                                               const float* __restrict__ B1,
                                               const float* __restrict__ attlmu,
                                               const float* __restrict__ attrmu,
                                               const float* __restrict__ attlls,
                                               const float* __restrict__ attrls,
                                               _Float16* __restrict__ C,
                                               float* __restrict__ alc,
                                               float* __restrict__ arc) {
    __shared__ _Float16 Braw[128 * 128];
    __shared__ _Float16 Bt[128 * 128];
    __shared__ _Float16 Cst[4][16 * 128];
    int t = threadIdx.x;
    stage_B(B0, B1, Braw, Bt, t);
    int wave = t >> 6, l = t & 63;
    int i16 = l & 15, q = l >> 4;
    float attL[8], attR[8];
#pragma unroll
    for (int tt = 0; tt < 8; ++tt) {
        int col = tt * 16 + i16;
        const float* la = (tt < 4) ? attlmu : attlls;
        const float* ra = (tt < 4) ? attrmu : attrls;
        attL[tt] = la[col & 63];
        attR[tt] = ra[col & 63];
    }
    int r0 = blockIdx.x * 64 + wave * 16;
    const _Float16* ar_ = A + (size_t)min(r0 + i16, N_NODES - 1) * 128;
    f16x8 a[4];
#pragma unroll
    for (int kb = 0; kb < 4; ++kb)
        a[kb] = *(const f16x8*)(ar_ + kb * 32 + q * 8);
    f32x4 acc[8];
    mfma_tile(a, Bt, acc, l);
    store_C(acc, &Cst[wave][0], C, r0, l);
    // attn epilogue: group g = tt>>1 (mu-h0, mu-h1, ls-h0, ls-h1)
    float pl[4][4], pr[4][4];
#pragma unroll
    for (int g = 0; g < 4; ++g)
#pragma unroll
        for (int r = 0; r < 4; ++r) {
            float sl = 0.f, sr = 0.f;
#pragma unroll
            for (int k = 0; k < 2; ++k) {
                float v = acc[g * 2 + k][r];
                sl += v * attL[g * 2 + k];
                sr += v * attR[g * 2 + k];
            }
            pl[g][r] = sl; pr[g][r] = sr;
        }
#pragma unroll
    for (int m = 1; m < 16; m <<= 1) {
#pragma unroll
        for (int g = 0; g < 4; ++g)
#pragma unroll
            for (int r = 0; r < 4; ++r) {
                pl[g][r] += __shfl_xor(pl[g][r], m);
                pr[g][r] += __shfl_xor(pr[g][r], m);
            }
    }
    if (i16 == 0) {
#pragma unroll
        for (int g = 0; g < 4; ++g)
#pragma unroll
            for (int r = 0; r < 4; ++r) {
                int row = r0 + q * 4 + r;
                bool sent = (row >= N_NODES);
                alc[row * 4 + g] = sent ? -1e30f : pl[g][r];
                arc[row * 4 + g] = sent ? 0.f : pr[g][r];
            }
    }
}

// ---------------------------------------------------------------- edge aggregation (padded, no validity logic)

__device__ __forceinline__ float sigmoidf_fast(float x) {
    return 1.f / (1.f + __expf(-x));
}

__device__ __forceinline__ float dot8_f16(f16x8 a, f16x8 b) {
    float part = 0.f;
#if __has_builtin(__builtin_amdgcn_fdot2)
    f16x2* pa = (f16x2*)&a;
    f16x2* pb = (f16x2*)&b;
#pragma unroll
    for (int kk = 0; kk < 4; ++kk)
        part = __builtin_amdgcn_fdot2(pa[kk], pb[kk], part, false);
#else
#pragma unroll
    for (int kk = 0; kk < 8; ++kk) part += (float)a[kk] * (float)b[kk];
#endif
    return part;
}

__device__ __forceinline__ float leaky_clamp(float x) {
    // med3(x, 0.2x, 60) == clamp(leaky_relu(x), -inf, 60)
    return __builtin_amdgcn_fmed3f(x, 0.2f * x, 60.f);
}

// layer 1: wave per dst node, quarter-wave (16 lanes x f16x8) per edge.
__global__ void __launch_bounds__(256) edge1_k(const _Float16* __restrict__ h1,
                                               const float* __restrict__ al,
                                               const float* __restrict__ ar,
                                               const int* __restrict__ offsets,
                                               const unsigned short* __restrict__ srcs,
                                               const float* __restrict__ b1,
                                               _Float16* __restrict__ h2o) {
    int i = (blockIdx.x * blockDim.x + threadIdx.x) >> 6;
    int l = threadIdx.x & 63;
    if (i >= N_NODES) return;
    int q = l & 15;
    int head = q >> 3;
    int sub = l >> 4;

    f16x8 hi8 = ((const f16x8*)(h1 + (size_t)i * 128))[q];
    float ari = ar[i * 2 + head];
    int start = offsets[i], end = offsets[i + 1];
    float s = 0.f;
    float o0 = 0.f, o1 = 0.f, o2 = 0.f, o3 = 0.f, o4 = 0.f, o5 = 0.f, o6 = 0.f, o7 = 0.f;

    int p2 = start + sub + 8;
    int j0 = srcs[start + sub];
    int j1 = srcs[start + sub + 4];
    int j2 = srcs[p2];
    f16x8 q0 = ((const f16x8*)(h1 + (size_t)j0 * 128))[q];
    f16x8 q1 = ((const f16x8*)(h1 + (size_t)j1 * 128))[q];
    f16x8 q2 = ((const f16x8*)(h1 + (size_t)j2 * 128))[q];
    float a0 = al[j0 * 2 + head];
    float a1 = al[j1 * 2 + head];
    float a2 = al[j2 * 2 + head];

#pragma unroll 3
    for (int pb = start; pb < end; pb += 4) {
        f16x8 hc = q0; float ac = a0;
        q0 = q1; a0 = a1;
        q1 = q2; a1 = a2;
        p2 += 4;
        int jn = srcs[p2];
        q2 = ((const f16x8*)(h1 + (size_t)jn * 128))[q];
        a2 = al[jn * 2 + head];

        float part = dot8_f16(hi8, hc);
        part += __shfl_xor(part, 1);
        part += __shfl_xor(part, 2);
        part += __shfl_xor(part, 4);
        float a = (ac + ari) * sigmoidf_fast(part);
        float w = __expf(leaky_clamp(a));
        s += w;
        o0 += w * (float)hc[0]; o1 += w * (float)hc[1];
        o2 += w * (float)hc[2]; o3 += w * (float)hc[3];
        o4 += w * (float)hc[4]; o5 += w * (float)hc[5];
        o6 += w * (float)hc[6]; o7 += w * (float)hc[7];
    }
    s  += __shfl_xor(s, 16);  s  += __shfl_xor(s, 32);
    o0 += __shfl_xor(o0, 16); o0 += __shfl_xor(o0, 32);
    o1 += __shfl_xor(o1, 16); o1 += __shfl_xor(o1, 32);
    o2 += __shfl_xor(o2, 16); o2 += __shfl_xor(o2, 32);
    o3 += __shfl_xor(o3, 16); o3 += __shfl_xor(o3, 32);
    o4 += __shfl_xor(o4, 16); o4 += __shfl_xor(o4, 32);
    o5 += __shfl_xor(o5, 16); o5 += __shfl_xor(o5, 32);
    o6 += __shfl_xor(o6, 16); o6 += __shfl_xor(o6, 32);
    o7 += __shfl_xor(o7, 16); o7 += __shfl_xor(o7, 32);
    if (l < 16) {
        float inv = 1.f / (s + 1e-16f);
        float4 bva = ((const float4*)b1)[l * 2];
        float4 bvb = ((const float4*)b1)[l * 2 + 1];
        float r0 = o0 * inv + bva.x, r1 = o1 * inv + bva.y;
        float r2 = o2 * inv + bva.z, r3 = o3 * inv + bva.w;
        float r4 = o4 * inv + bvb.x, r5 = o5 * inv + bvb.y;
        float r6 = o6 * inv + bvb.z, r7 = o7 * inv + bvb.w;
        r0 = (r0 > 0.f) ? r0 : (__expf(r0) - 1.f);
        r1 = (r1 > 0.f) ? r1 : (__expf(r1) - 1.f);
        r2 = (r2 > 0.f) ? r2 : (__expf(r2) - 1.f);
        r3 = (r3 > 0.f) ? r3 : (__expf(r3) - 1.f);
        r4 = (r4 > 0.f) ? r4 : (__expf(r4) - 1.f);
        r5 = (r5 > 0.f) ? r5 : (__expf(r5) - 1.f);
        r6 = (r6 > 0.f) ? r6 : (__expf(r6) - 1.f);
        r7 = (r7 > 0.f) ? r7 : (__expf(r7) - 1.f);
        f16x8 r;
        r[0] = (_Float16)r0; r[1] = (_Float16)r1; r[2] = (_Float16)r2; r[3] = (_Float16)r3;
        r[4] = (_Float16)r4; r[5] = (_Float16)r5; r[6] = (_Float16)r6; r[7] = (_Float16)r7;
        ((f16x8*)(h2o + (size_t)i * 128))[l] = r;
    }
}

// layers 2+3 fused: wave per dst node, quarter-wave per edge; writes d_out.
__global__ void __launch_bounds__(256) edge23_k(const _Float16* __restrict__ hcat,
                                                const float* __restrict__ alc,
                                                const float* __restrict__ arc,
                                                const int* __restrict__ offsets,
                                                const unsigned short* __restrict__ srcs,
                                                const float* __restrict__ bmu,
                                                const float* __restrict__ bls,
                                                float* __restrict__ out) {
    int i = (blockIdx.x * blockDim.x + threadIdx.x) >> 6;
    int l = threadIdx.x & 63;
    if (i >= N_NODES) return;
    int q = l & 15;
    int g = (l >> 2) & 3;
    int sub = l >> 4;

    f16x8 hi8 = ((const f16x8*)(hcat + (size_t)i * 128))[q];
    float ari = arc[i * 4 + g];
    int start = offsets[i], end = offsets[i + 1];
    float s = 0.f;
    float o0 = 0.f, o1 = 0.f, o2 = 0.f, o3 = 0.f, o4 = 0.f, o5 = 0.f, o6 = 0.f, o7 = 0.f;

    int p2 = start + sub + 8;
    int j0 = srcs[start + sub];
    int j1 = srcs[start + sub + 4];
    int j2 = srcs[p2];
    f16x8 q0 = ((const f16x8*)(hcat + (size_t)j0 * 128))[q];
    f16x8 q1 = ((const f16x8*)(hcat + (size_t)j1 * 128))[q];
    f16x8 q2 = ((const f16x8*)(hcat + (size_t)j2 * 128))[q];
    float a0 = alc[j0 * 4 + g];
    float a1 = alc[j1 * 4 + g];
    float a2 = alc[j2 * 4 + g];

#pragma unroll 3
    for (int pb = start; pb < end; pb += 4) {
        f16x8 hc = q0; float ac = a0;
        q0 = q1; a0 = a1;
        q1 = q2; a1 = a2;
        p2 += 4;
        int jn = srcs[p2];
        q2 = ((const f16x8*)(hcat + (size_t)jn * 128))[q];
        a2 = alc[jn * 4 + g];

        float part = dot8_f16(hi8, hc);
        part += __shfl_xor(part, 1);
        part += __shfl_xor(part, 2);
        float a = (ac + ari) * sigmoidf_fast(part);
        float w = __expf(leaky_clamp(a));
        s += w;
        o0 += w * (float)hc[0]; o1 += w * (float)hc[1];
        o2 += w * (float)hc[2]; o3 += w * (float)hc[3];
        o4 += w * (float)hc[4]; o5 += w * (float)hc[5];
        o6 += w * (float)hc[6]; o7 += w * (float)hc[7];
    }
    s  += __shfl_xor(s, 16);  s  += __shfl_xor(s, 32);
    o0 += __shfl_xor(o0, 16); o0 += __shfl_xor(o0, 32);
    o1 += __shfl_xor(o1, 16); o1 += __shfl_xor(o1, 32);
    o2 += __shfl_xor(o2, 16); o2 += __shfl_xor(o2, 32);
    o3 += __shfl_xor(o3, 16); o3 += __shfl_xor(o3, 32);
    o4 += __shfl_xor(o4, 16); o4 += __shfl_xor(o4, 32);
    o5 += __shfl_xor(o5, 16); o5 += __shfl_xor(o5, 32);
    o6 += __shfl_xor(o6, 16); o6 += __shfl_xor(o6, 32);
    o7 += __shfl_xor(o7, 16); o7 += __shfl_xor(o7, 32);
    if (l < 16) {
        float inv = 1.f / (s + 1e-16f);
        int br = l >> 3;
        int c0 = 8 * (l & 7);
        const float* b = br ? bls : bmu;
        float4 bva = ((const float4*)(b + c0))[0];
        float4 bvb = ((const float4*)(b + c0))[1];
        float4 ra, rb;
        ra.x = o0 * inv + bva.x; ra.y = o1 * inv + bva.y;
        ra.z = o2 * inv + bva.z; ra.w = o3 * inv + bva.w;
        rb.x = o4 * inv + bvb.x; rb.y = o5 * inv + bvb.y;
        rb.z = o6 * inv + bvb.z; rb.w = o7 * inv + bvb.w;
        float* dst = out + (size_t)br * (N_NODES * 64) + (size_t)i * 64 + c0;
        ((float4*)dst)[0] = ra;
        ((float4*)dst)[1] = rb;
    }
}

// ---------------------------------------------------------------- launcher

extern "C" void kernel_launch(void* const* d_in, const int* in_sizes, int n_in,
                              void* d_out, int out_size, void* d_ws, size_t ws_size,
                              hipStream_t stream) {
    const float* x      = (const float*)d_in[0];
    const int*   ei     = (const int*)d_in[1];
    const float* W1     = (const float*)d_in[2];
    const float* att_l1 = (const float*)d_in[3];
    const float* att_r1 = (const float*)d_in[4];
    const float* b1     = (const float*)d_in[5];
    const float* Wmu    = (const float*)d_in[6];
    const float* attlmu = (const float*)d_in[7];
    const float* attrmu = (const float*)d_in[8];
    const float* bmu    = (const float*)d_in[9];
    const float* Wls    = (const float*)d_in[10];
    const float* attlls = (const float*)d_in[11];
    const float* attrls = (const float*)d_in[12];
    const float* bls    = (const float*)d_in[13];
    float* out = (float*)d_out;

    _Float16* h1   = (_Float16*)d_ws;          // NROWS*128 halfs
    _Float16* h2   = h1 + (size_t)NROWS * 128;
    _Float16* hcat = h2 + (size_t)NROWS * 128;
    float* al1   = (float*)(hcat + (size_t)NROWS * 128);  // NROWS*2
    float* ar1   = al1 + NROWS * 2;
    float* alc   = ar1 + NROWS * 2;            // NROWS*4
    float* arc   = alc + NROWS * 4;
    int* counts  = (int*)(arc + NROWS * 4);    // 50,000
    int* fill    = counts + 50000;             // 50,000
    int* offsets = fill + 50000;               // 50,016
    unsigned short* srcs = (unsigned short*)(offsets + 50016);  // 1,000,064 ushorts
    int* bsums   = (int*)(srcs + 1000064);     // 256
    int* bbase   = bsums + 256;                // 256

    hipMemsetAsync(counts, 0, 50000 * sizeof(int), stream);
    hipMemsetAsync(fill, 0, 50000 * sizeof(int), stream);

    hist_k<<<NCHUNK * NPART, 256, 0, stream>>>(ei, counts);
    reduce_k<<<SCAN_BLOCKS, 256, 0, stream>>>(counts, bsums);
    scansums_k<<<1, 256, 0, stream>>>(bsums, bbase);
    scanblk_k<<<SCAN_BLOCKS, 256, 0, stream>>>(counts, bbase, offsets);
    scatter_k<<<NCHUNK * NPART, 256, 0, stream>>>(ei, offsets, fill, srcs);
    pad_k<<<SCAN_BLOCKS, 256, 0, stream>>>(counts, offsets, srcs);

    gemm1_k<<<GEMM_TILES, 256, 0, stream>>>(x, W1, att_l1, att_r1, h1, al1, ar1);

    int nblocks = (N_NODES + 3) / 4;       // edge kernels: 4 waves (nodes) / block
    edge1_k<<<nblocks, 256, 0, stream>>>(h1, al1, ar1, offsets, srcs, b1, h2);

    gemm2_k<<<GEMM_TILES, 256, 0, stream>>>(h2, Wmu, Wls, attlmu, attrmu, attlls, attrls,
                                            hcat, alc, arc);
    edge23_k<<<nblocks, 256, 0, stream>>>(hcat, alc, arc, offsets, srcs, bmu, bls, out);
}